// Round 3
// baseline (215.276 us; speedup 1.0000x reference)
//
#include <hip/hip_runtime.h>
#include <hip/hip_bf16.h>
#include <math.h>

typedef __hip_bfloat16 bf16;
typedef __attribute__((ext_vector_type(4))) float f32x4;
typedef __attribute__((ext_vector_type(8))) short s16x8;

#define B_     2
#define DIM_   512
#define Hh     48
#define Ww     48
#define T_     2304
#define HEADS_ 8
#define HD_    64
#define NS_    7
#define R_     3
#define KK_    49

#define LDSTR  40   // padded LDS row stride (elems) for [64][32] tiles

__device__ __forceinline__ short f2bs(float f) {
    bf16 h = __float2bfloat16(f);
    return *(short*)&h;
}

// load 8 contiguous fp32, convert to 8 bf16 (as shorts)
__device__ __forceinline__ s16x8 cvt8(const float* __restrict__ p) {
    f32x4 a = *(const f32x4*)p;
    f32x4 b = *(const f32x4*)(p + 4);
    s16x8 r;
    r[0] = f2bs(a[0]); r[1] = f2bs(a[1]); r[2] = f2bs(a[2]); r[3] = f2bs(a[3]);
    r[4] = f2bs(b[0]); r[5] = f2bs(b[1]); r[6] = f2bs(b[2]); r[7] = f2bs(b[3]);
    return r;
}

// ---------------------------------------------------------------------------
// QKV projection GEMM: D[t][o] = sum_c X[c][t] * W[o][c] + bias[o]
// fp32 inputs -> bf16 LDS tiles. Output token-major fp32 into ws.
// grid: (T/64, 1536/64, B), block 256 (4 waves). Tile 64x64, BK=32.
// ---------------------------------------------------------------------------
__global__ __launch_bounds__(256) void gemm_qkv(
    const float* __restrict__ x,
    const float* __restrict__ wq, const float* __restrict__ bq,
    const float* __restrict__ wk, const float* __restrict__ bk,
    const float* __restrict__ wv, const float* __restrict__ bv,
    float* __restrict__ qt, float* __restrict__ kt, float* __restrict__ vt)
{
    const int tt   = blockIdx.x * 64;          // token tile base
    const int ot   = blockIdx.y * 64;          // stacked output channel tile [0,1536)
    const int b    = blockIdx.z;
    const int proj = ot >> 9;                  // 0=q 1=k 2=v
    const int orow = ot & 511;                 // channel base within proj
    const int head = orow >> 6;

    const float* W    = (proj == 0) ? wq : (proj == 1) ? wk : wv;
    const float* bsel = (proj == 0) ? bq : (proj == 1) ? bk : bv;
    float*       osel = (proj == 0) ? qt : (proj == 1) ? kt : vt;

    const float* X = x + (size_t)b * DIM_ * T_;

    __shared__ __align__(16) short Ws[64 * LDSTR];  // [o][c]
    __shared__ __align__(16) short Xs[64 * LDSTR];  // [t][c] (transposed)

    const int tid  = threadIdx.x;
    const int lane = tid & 63;
    const int wid  = tid >> 6;

    // staging assignments
    const int wrow = tid >> 2;          // 0..63 (W row)
    const int wcq  = (tid & 3) * 8;     // k-chunk
    const int xc   = tid >> 3;          // 0..31 (X row = channel)
    const int xtq  = (tid & 7) * 8;     // token chunk

    f32x4 acc[4];
#pragma unroll
    for (int n = 0; n < 4; ++n) acc[n] = (f32x4){0.f, 0.f, 0.f, 0.f};

    for (int kk = 0; kk < DIM_; kk += 32) {
        // stage W tile [64][32]
        *(s16x8*)(&Ws[wrow * LDSTR + wcq]) =
            cvt8(W + (size_t)(orow + wrow) * DIM_ + kk + wcq);
        // stage X tile transposed -> Xs[t][c]
        s16x8 xv8 = cvt8(X + (size_t)(kk + xc) * T_ + tt + xtq);
#pragma unroll
        for (int e = 0; e < 8; ++e) Xs[(xtq + e) * LDSTR + xc] = xv8[e];
        __syncthreads();

        // fragments: A rows = tokens (wave's 16 rows), B rows (cols of D) = o
        s16x8 a = *(const s16x8*)(&Xs[(wid * 16 + (lane & 15)) * LDSTR + 8 * (lane >> 4)]);
#pragma unroll
        for (int n = 0; n < 4; ++n) {
            s16x8 bf = *(const s16x8*)(&Ws[(n * 16 + (lane & 15)) * LDSTR + 8 * (lane >> 4)]);
            acc[n] = __builtin_amdgcn_mfma_f32_16x16x32_bf16(a, bf, acc[n], 0, 0, 0);
        }
        __syncthreads();
    }

    // epilogue: D row = token, col = o. C/D map: col = lane&15, row = (lane>>4)*4+e
    float* obase = osel + (size_t)(b * HEADS_ + head) * T_ * HD_;
#pragma unroll
    for (int n = 0; n < 4; ++n) {
        const int d    = n * 16 + (lane & 15);                 // dim within head
        const float bi = bsel[orow + d];
#pragma unroll
        for (int e = 0; e < 4; ++e) {
            const int t = tt + wid * 16 + (lane >> 4) * 4 + e;
            obase[(size_t)t * HD_ + d] = acc[n][e] + bi;
        }
    }
}

// ---------------------------------------------------------------------------
// Output projection GEMM: D[o][t] = sum_c W[o][c] * AO[c][t] + bias[o]
// W fp32 -> bf16; AO already bf16 in ws. Output channel-major FP32 (d_out).
// grid: (T/64, 512/64, B), block 256.
// ---------------------------------------------------------------------------
__global__ __launch_bounds__(256) void gemm_out(
    const bf16* __restrict__ ao,
    const float* __restrict__ wo, const float* __restrict__ bo,
    float* __restrict__ out)
{
    const int tt = blockIdx.x * 64;
    const int ot = blockIdx.y * 64;
    const int b  = blockIdx.z;

    const short* X = (const short*)ao + (size_t)b * DIM_ * T_;

    __shared__ __align__(16) short Ws[64 * LDSTR];
    __shared__ __align__(16) short Xs[64 * LDSTR];

    const int tid  = threadIdx.x;
    const int lane = tid & 63;
    const int wid  = tid >> 6;

    const int wrow = tid >> 2;
    const int wcq  = (tid & 3) * 8;
    const int xc   = tid >> 3;
    const int xtq  = (tid & 7) * 8;

    f32x4 acc[4];
#pragma unroll
    for (int n = 0; n < 4; ++n) acc[n] = (f32x4){0.f, 0.f, 0.f, 0.f};

    for (int kk = 0; kk < DIM_; kk += 32) {
        *(s16x8*)(&Ws[wrow * LDSTR + wcq]) =
            cvt8(wo + (size_t)(ot + wrow) * DIM_ + kk + wcq);
        s16x8 xv8 = *(const s16x8*)(X + (size_t)(kk + xc) * T_ + tt + xtq);
#pragma unroll
        for (int e = 0; e < 8; ++e) Xs[(xtq + e) * LDSTR + xc] = xv8[e];
        __syncthreads();

        // A rows = o (wave's 16 rows), B cols = tokens
        s16x8 a = *(const s16x8*)(&Ws[(wid * 16 + (lane & 15)) * LDSTR + 8 * (lane >> 4)]);
#pragma unroll
        for (int n = 0; n < 4; ++n) {
            s16x8 bf = *(const s16x8*)(&Xs[(n * 16 + (lane & 15)) * LDSTR + 8 * (lane >> 4)]);
            acc[n] = __builtin_amdgcn_mfma_f32_16x16x32_bf16(a, bf, acc[n], 0, 0, 0);
        }
        __syncthreads();
    }

    float* obase = out + (size_t)b * DIM_ * T_;
#pragma unroll
    for (int n = 0; n < 4; ++n) {
        const int t = tt + n * 16 + (lane & 15);
#pragma unroll
        for (int e = 0; e < 4; ++e) {
            const int o    = ot + wid * 16 + (lane >> 4) * 4 + e;
            obase[(size_t)o * T_ + t] = acc[n][e] + bo[o];
        }
    }
}

// ---------------------------------------------------------------------------
// Neighborhood attention + self-value rejection. One thread per (b,h,token).
// q,k,v token-major fp32 in ws. Writes ao channel-major bf16 [B][512][T].
// grid: B*H*T/64 blocks of 64.
// ---------------------------------------------------------------------------
__global__ __launch_bounds__(64) void attn_kernel(
    const float* __restrict__ qt, const float* __restrict__ kt,
    const float* __restrict__ vt, bf16* __restrict__ ao)
{
    const int gid = blockIdx.x * 64 + threadIdx.x;
    const int t   = gid % T_;
    const int bh  = gid / T_;
    const int y   = t / Ww, x = t % Ww;

    const float* qp = qt + ((size_t)bh * T_ + t) * HD_;
    const float* kb = kt + (size_t)bh * T_ * HD_;
    const float* vb = vt + (size_t)bh * T_ * HD_;

    float q[HD_];
#pragma unroll
    for (int i = 0; i < 16; ++i) {
        f32x4 v4 = *(const f32x4*)(qp + 4 * i);
        q[4*i+0] = v4[0]; q[4*i+1] = v4[1]; q[4*i+2] = v4[2]; q[4*i+3] = v4[3];
    }

    float s[KK_];
    float m = -3.0e38f;
#pragma unroll
    for (int j = 0; j < KK_; ++j) {
        const int ny = y + j / NS_ - R_;
        const int nx = x + j % NS_ - R_;
        if (ny >= 0 && ny < Hh && nx >= 0 && nx < Ww) {
            const float* kp = kb + (size_t)(ny * Ww + nx) * HD_;
            float dot = 0.f;
#pragma unroll
            for (int i = 0; i < 16; ++i) {
                f32x4 k4 = *(const f32x4*)(kp + 4 * i);
                dot += q[4*i+0]*k4[0] + q[4*i+1]*k4[1] + q[4*i+2]*k4[2] + q[4*i+3]*k4[3];
            }
            s[j] = dot * 0.125f;   // HD^-0.5
            m = fmaxf(m, s[j]);
        } else {
            s[j] = -3.0e38f;
        }
    }

    float sum = 0.f;
#pragma unroll
    for (int j = 0; j < KK_; ++j) { s[j] = __expf(s[j] - m); sum += s[j]; }
    const float inv = 1.0f / sum;

    float o[HD_];
#pragma unroll
    for (int i = 0; i < HD_; ++i) o[i] = 0.f;
#pragma unroll
    for (int j = 0; j < KK_; ++j) {
        const int ny = y + j / NS_ - R_;
        const int nx = x + j % NS_ - R_;
        if (ny >= 0 && ny < Hh && nx >= 0 && nx < Ww) {
            const float p = s[j] * inv;
            const float* vp = vb + (size_t)(ny * Ww + nx) * HD_;
#pragma unroll
            for (int i = 0; i < 16; ++i) {
                f32x4 v4 = *(const f32x4*)(vp + 4 * i);
                o[4*i+0] += p * v4[0]; o[4*i+1] += p * v4[1];
                o[4*i+2] += p * v4[2]; o[4*i+3] += p * v4[3];
            }
        }
    }

    // subtract component along unit self-value vector
    const float* vp = vb + (size_t)t * HD_;
    float n2 = 0.f, dot = 0.f;
#pragma unroll
    for (int i = 0; i < 16; ++i) {
        f32x4 v4 = *(const f32x4*)(vp + 4 * i);
        n2  += v4[0]*v4[0] + v4[1]*v4[1] + v4[2]*v4[2] + v4[3]*v4[3];
        dot += o[4*i+0]*v4[0] + o[4*i+1]*v4[1] + o[4*i+2]*v4[2] + o[4*i+3]*v4[3];
    }
    const float mx    = fmaxf(sqrtf(n2), 1e-12f);
    const float coeff = dot / (mx * mx);

    const int b = bh >> 3, h = bh & 7;
    bf16* aop = ao + (size_t)(b * DIM_ + h * HD_) * T_ + t;
#pragma unroll
    for (int i = 0; i < 16; ++i) {
        f32x4 v4 = *(const f32x4*)(vp + 4 * i);
        aop[(size_t)(4*i+0) * T_] = __float2bfloat16(o[4*i+0] - coeff * v4[0]);
        aop[(size_t)(4*i+1) * T_] = __float2bfloat16(o[4*i+1] - coeff * v4[1]);
        aop[(size_t)(4*i+2) * T_] = __float2bfloat16(o[4*i+2] - coeff * v4[2]);
        aop[(size_t)(4*i+3) * T_] = __float2bfloat16(o[4*i+3] - coeff * v4[3]);
    }
}

// ---------------------------------------------------------------------------
extern "C" void kernel_launch(void* const* d_in, const int* in_sizes, int n_in,
                              void* d_out, int out_size, void* d_ws, size_t ws_size,
                              hipStream_t stream)
{
    (void)in_sizes; (void)n_in; (void)out_size; (void)ws_size;

    const float* x  = (const float*)d_in[0];
    const float* wq = (const float*)d_in[1];
    const float* bq = (const float*)d_in[2];
    const float* wk = (const float*)d_in[3];
    const float* bk = (const float*)d_in[4];
    const float* wv = (const float*)d_in[5];
    const float* bv = (const float*)d_in[6];
    const float* wo = (const float*)d_in[7];
    const float* bo = (const float*)d_in[8];
    float* out = (float*)d_out;   // reference output dtype is float32

    // workspace layout (fp32 q,k,v token-major; bf16 ao channel-major) ~33 MB
    const size_t per = (size_t)B_ * HEADS_ * T_ * HD_;   // 2359296
    float* qt = (float*)d_ws;
    float* kt = qt + per;
    float* vt = kt + per;
    bf16*  ao = (bf16*)(vt + per);

    dim3 g1(T_ / 64, 1536 / 64, B_);
    gemm_qkv<<<g1, 256, 0, stream>>>(x, wq, bq, wk, bk, wv, bv, qt, kt, vt);

    attn_kernel<<<dim3((B_ * HEADS_ * T_) / 64), 64, 0, stream>>>(qt, kt, vt, ao);

    dim3 g2(T_ / 64, DIM_ / 64, B_);
    gemm_out<<<g2, 256, 0, stream>>>(ao, wo, bo, out);
}

// Round 4
// 145.749 us; speedup vs baseline: 1.4770x; 1.4770x over previous
//
#include <hip/hip_runtime.h>
#include <hip/hip_bf16.h>
#include <math.h>

typedef __hip_bfloat16 bf16;
typedef __attribute__((ext_vector_type(4))) float f32x4;
typedef __attribute__((ext_vector_type(8))) short s16x8;

#define B_     2
#define DIM_   512
#define Hh     48
#define Ww     48
#define T_     2304
#define HEADS_ 8
#define HD_    64
#define NS_    7
#define R_     3
#define KK_    49

#define LDSTR  40   // padded LDS row stride (elems) for [64][32] tiles

__device__ __forceinline__ short f2bs(float f) {
    bf16 h = __float2bfloat16(f);
    return *(short*)&h;
}

// load 8 contiguous fp32, convert to 8 bf16 (as shorts)
__device__ __forceinline__ s16x8 cvt8(const float* __restrict__ p) {
    f32x4 a = *(const f32x4*)p;
    f32x4 b = *(const f32x4*)(p + 4);
    s16x8 r;
    r[0] = f2bs(a[0]); r[1] = f2bs(a[1]); r[2] = f2bs(a[2]); r[3] = f2bs(a[3]);
    r[4] = f2bs(b[0]); r[5] = f2bs(b[1]); r[6] = f2bs(b[2]); r[7] = f2bs(b[3]);
    return r;
}

// ---------------------------------------------------------------------------
// QKV projection GEMM: D[t][o] = sum_c X[c][t] * W[o][c] + bias[o]
// fp32 inputs -> bf16 LDS tiles. Output token-major fp32 into ws.
// grid: (T/64, 1536/64, B), block 256 (4 waves). Tile 64x64, BK=32.
// ---------------------------------------------------------------------------
__global__ __launch_bounds__(256) void gemm_qkv(
    const float* __restrict__ x,
    const float* __restrict__ wq, const float* __restrict__ bq,
    const float* __restrict__ wk, const float* __restrict__ bk,
    const float* __restrict__ wv, const float* __restrict__ bv,
    float* __restrict__ qt, float* __restrict__ kt, float* __restrict__ vt)
{
    const int tt   = blockIdx.x * 64;          // token tile base
    const int ot   = blockIdx.y * 64;          // stacked output channel tile [0,1536)
    const int b    = blockIdx.z;
    const int proj = ot >> 9;                  // 0=q 1=k 2=v
    const int orow = ot & 511;                 // channel base within proj
    const int head = orow >> 6;

    const float* W    = (proj == 0) ? wq : (proj == 1) ? wk : wv;
    const float* bsel = (proj == 0) ? bq : (proj == 1) ? bk : bv;
    float*       osel = (proj == 0) ? qt : (proj == 1) ? kt : vt;

    const float* X = x + (size_t)b * DIM_ * T_;

    __shared__ __align__(16) short Ws[64 * LDSTR];  // [o][c]
    __shared__ __align__(16) short Xs[64 * LDSTR];  // [t][c] (transposed)

    const int tid  = threadIdx.x;
    const int lane = tid & 63;
    const int wid  = tid >> 6;

    // staging assignments
    const int wrow = tid >> 2;          // 0..63 (W row)
    const int wcq  = (tid & 3) * 8;     // k-chunk
    const int xc   = tid >> 3;          // 0..31 (X row = channel)
    const int xtq  = (tid & 7) * 8;     // token chunk

    f32x4 acc[4];
#pragma unroll
    for (int n = 0; n < 4; ++n) acc[n] = (f32x4){0.f, 0.f, 0.f, 0.f};

    for (int kk = 0; kk < DIM_; kk += 32) {
        // stage W tile [64][32]
        *(s16x8*)(&Ws[wrow * LDSTR + wcq]) =
            cvt8(W + (size_t)(orow + wrow) * DIM_ + kk + wcq);
        // stage X tile transposed -> Xs[t][c]
        s16x8 xv8 = cvt8(X + (size_t)(kk + xc) * T_ + tt + xtq);
#pragma unroll
        for (int e = 0; e < 8; ++e) Xs[(xtq + e) * LDSTR + xc] = xv8[e];
        __syncthreads();

        // fragments: A rows = tokens (wave's 16 rows), B rows (cols of D) = o
        s16x8 a = *(const s16x8*)(&Xs[(wid * 16 + (lane & 15)) * LDSTR + 8 * (lane >> 4)]);
#pragma unroll
        for (int n = 0; n < 4; ++n) {
            s16x8 bf = *(const s16x8*)(&Ws[(n * 16 + (lane & 15)) * LDSTR + 8 * (lane >> 4)]);
            acc[n] = __builtin_amdgcn_mfma_f32_16x16x32_bf16(a, bf, acc[n], 0, 0, 0);
        }
        __syncthreads();
    }

    // epilogue: D row = token, col = o. C/D map: col = lane&15, row = (lane>>4)*4+e
    float* obase = osel + (size_t)(b * HEADS_ + head) * T_ * HD_;
#pragma unroll
    for (int n = 0; n < 4; ++n) {
        const int d    = n * 16 + (lane & 15);                 // dim within head
        const float bi = bsel[orow + d];
#pragma unroll
        for (int e = 0; e < 4; ++e) {
            const int t = tt + wid * 16 + (lane >> 4) * 4 + e;
            obase[(size_t)t * HD_ + d] = acc[n][e] + bi;
        }
    }
}

// ---------------------------------------------------------------------------
// Output projection GEMM: D[o][t] = sum_c W[o][c] * AO_t[t][c] + bias[o]
// W fp32 -> bf16; AO token-major bf16 in ws (direct contiguous staging).
// Output channel-major FP32 (d_out). grid: (T/64, 512/64, B), block 256.
// ---------------------------------------------------------------------------
__global__ __launch_bounds__(256) void gemm_out(
    const bf16* __restrict__ ao,
    const float* __restrict__ wo, const float* __restrict__ bo,
    float* __restrict__ out)
{
    const int tt = blockIdx.x * 64;
    const int ot = blockIdx.y * 64;
    const int b  = blockIdx.z;

    const short* X = (const short*)ao + (size_t)b * T_ * DIM_;  // token-major [T][DIM]

    __shared__ __align__(16) short Ws[64 * LDSTR];  // [o][c]
    __shared__ __align__(16) short Xs[64 * LDSTR];  // [t][c]

    const int tid  = threadIdx.x;
    const int lane = tid & 63;
    const int wid  = tid >> 6;

    const int row = tid >> 2;          // 0..63
    const int cq  = (tid & 3) * 8;     // k-chunk

    f32x4 acc[4];
#pragma unroll
    for (int n = 0; n < 4; ++n) acc[n] = (f32x4){0.f, 0.f, 0.f, 0.f};

    for (int kk = 0; kk < DIM_; kk += 32) {
        *(s16x8*)(&Ws[row * LDSTR + cq]) =
            cvt8(wo + (size_t)(ot + row) * DIM_ + kk + cq);
        *(s16x8*)(&Xs[row * LDSTR + cq]) =
            *(const s16x8*)(X + (size_t)(tt + row) * DIM_ + kk + cq);
        __syncthreads();

        // A rows = o (wave's 16 rows), B cols = tokens
        s16x8 a = *(const s16x8*)(&Ws[(wid * 16 + (lane & 15)) * LDSTR + 8 * (lane >> 4)]);
#pragma unroll
        for (int n = 0; n < 4; ++n) {
            s16x8 bf = *(const s16x8*)(&Xs[(n * 16 + (lane & 15)) * LDSTR + 8 * (lane >> 4)]);
            acc[n] = __builtin_amdgcn_mfma_f32_16x16x32_bf16(a, bf, acc[n], 0, 0, 0);
        }
        __syncthreads();
    }

    float* obase = out + (size_t)b * DIM_ * T_;
#pragma unroll
    for (int n = 0; n < 4; ++n) {
        const int t = tt + n * 16 + (lane & 15);
#pragma unroll
        for (int e = 0; e < 4; ++e) {
            const int o    = ot + wid * 16 + (lane >> 4) * 4 + e;
            obase[(size_t)o * T_ + t] = acc[n][e] + bo[o];
        }
    }
}

// ---------------------------------------------------------------------------
// Neighborhood attention + self-value rejection. ONE WAVE per (b,h,token).
// Phase 1: lane j = neighbor j (j<49), full 64-dim dot.
// Phase 2: lane d = output dim d, p_j via shuffle broadcast, coalesced V rows.
// q,k,v token-major fp32 in ws. Writes ao TOKEN-major bf16 [B][T][512].
// grid: B*H*T/4 blocks of 256 (4 waves/block).
// ---------------------------------------------------------------------------
__global__ __launch_bounds__(256) void attn_kernel(
    const float* __restrict__ qt, const float* __restrict__ kt,
    const float* __restrict__ vt, bf16* __restrict__ ao)
{
    const int lane = threadIdx.x & 63;
    const int gw   = blockIdx.x * 4 + (threadIdx.x >> 6);   // global wave id
    const int t    = gw % T_;
    const int bh   = gw / T_;
    const int y    = t / Ww, x = t % Ww;

    const float* qp = qt + ((size_t)bh * T_ + t) * HD_;
    const float* kb = kt + (size_t)bh * T_ * HD_;
    const float* vb = vt + (size_t)bh * T_ * HD_;

    // ---- phase 1: scores (lane = neighbor) ----
    float s = -3.0e38f;
    if (lane < KK_) {
        const int ny = y + lane / NS_ - R_;
        const int nx = x + lane % NS_ - R_;
        const bool valid = (ny >= 0) & (ny < Hh) & (nx >= 0) & (nx < Ww);
        const int nyc = min(max(ny, 0), Hh - 1);
        const int nxc = min(max(nx, 0), Ww - 1);
        const float* kp = kb + (size_t)(nyc * Ww + nxc) * HD_;
        float dot = 0.f;
#pragma unroll
        for (int i = 0; i < 16; ++i) {
            f32x4 k4 = *(const f32x4*)(kp + 4 * i);
            f32x4 q4 = *(const f32x4*)(qp + 4 * i);
            dot += q4[0]*k4[0] + q4[1]*k4[1] + q4[2]*k4[2] + q4[3]*k4[3];
        }
        s = valid ? dot * 0.125f : -3.0e38f;
    }

    // wave-wide softmax
    float m = s;
#pragma unroll
    for (int off = 32; off; off >>= 1) m = fmaxf(m, __shfl_xor(m, off));
    float p = __expf(s - m);                 // invalid/tail lanes -> exp(-inf)=0
    float sum = p;
#pragma unroll
    for (int off = 32; off; off >>= 1) sum += __shfl_xor(sum, off);
    p *= 1.0f / sum;

    // ---- phase 2: PV (lane = dim) ----
    const int d = lane;
    float o_d = 0.f;
#pragma unroll
    for (int j = 0; j < KK_; ++j) {
        const int ny  = min(max(y + j / NS_ - R_, 0), Hh - 1);
        const int nx  = min(max(x + j % NS_ - R_, 0), Ww - 1);
        const float pj = __shfl(p, j);
        o_d += pj * vb[(size_t)(ny * Ww + nx) * HD_ + d];
    }

    // ---- self-value rejection ----
    const float vs = vb[(size_t)t * HD_ + d];
    float n2 = vs * vs;
#pragma unroll
    for (int off = 32; off; off >>= 1) n2 += __shfl_xor(n2, off);
    float odv = o_d * vs;
#pragma unroll
    for (int off = 32; off; off >>= 1) odv += __shfl_xor(odv, off);
    const float mx    = fmaxf(sqrtf(n2), 1e-12f);
    const float coeff = odv / (mx * mx);

    // ---- store token-major (coalesced 128B/wave) ----
    const int b = bh >> 3, h = bh & 7;
    ao[((size_t)b * T_ + t) * DIM_ + h * HD_ + d] = __float2bfloat16(o_d - coeff * vs);
}

// ---------------------------------------------------------------------------
extern "C" void kernel_launch(void* const* d_in, const int* in_sizes, int n_in,
                              void* d_out, int out_size, void* d_ws, size_t ws_size,
                              hipStream_t stream)
{
    (void)in_sizes; (void)n_in; (void)out_size; (void)ws_size;

    const float* x  = (const float*)d_in[0];
    const float* wq = (const float*)d_in[1];
    const float* bq = (const float*)d_in[2];
    const float* wk = (const float*)d_in[3];
    const float* bk = (const float*)d_in[4];
    const float* wv = (const float*)d_in[5];
    const float* bv = (const float*)d_in[6];
    const float* wo = (const float*)d_in[7];
    const float* bo = (const float*)d_in[8];
    float* out = (float*)d_out;   // reference output dtype is float32

    // workspace layout (fp32 q,k,v token-major; bf16 ao token-major) ~33 MB
    const size_t per = (size_t)B_ * HEADS_ * T_ * HD_;   // 2359296
    float* qt = (float*)d_ws;
    float* kt = qt + per;
    float* vt = kt + per;
    bf16*  ao = (bf16*)(vt + per);

    dim3 g1(T_ / 64, 1536 / 64, B_);
    gemm_qkv<<<g1, 256, 0, stream>>>(x, wq, bq, wk, bk, wv, bv, qt, kt, vt);

    attn_kernel<<<dim3((B_ * HEADS_ * T_) / 4), 256, 0, stream>>>(qt, kt, vt, ao);

    dim3 g2(T_ / 64, DIM_ / 64, B_);
    gemm_out<<<g2, 256, 0, stream>>>(ao, wo, bo, out);
}

// Round 6
// 122.272 us; speedup vs baseline: 1.7606x; 1.1920x over previous
//
#include <hip/hip_runtime.h>
#include <hip/hip_bf16.h>
#include <math.h>

typedef __hip_bfloat16 bf16;
typedef __attribute__((ext_vector_type(4))) float f32x4;
typedef __attribute__((ext_vector_type(8))) short s16x8;

#define B_     2
#define DIM_   512
#define Hh     48
#define Ww     48
#define T_     2304
#define HEADS_ 8
#define HD_    64
#define NS_    7
#define R_     3
#define KK_    49

#define LDSTR  40   // padded LDS row stride (elems) for [64][32] GEMM tiles

#define WROWS  154  // 7 * 22 neighborhood window rows for a 16-token chunk

__device__ __forceinline__ short f2bs(float f) {
    bf16 h = __float2bfloat16(f);
    return *(short*)&h;
}

// load 8 contiguous fp32, convert to 8 bf16 (as shorts)
__device__ __forceinline__ s16x8 cvt8(const float* __restrict__ p) {
    f32x4 a = *(const f32x4*)p;
    f32x4 b = *(const f32x4*)(p + 4);
    s16x8 r;
    r[0] = f2bs(a[0]); r[1] = f2bs(a[1]); r[2] = f2bs(a[2]); r[3] = f2bs(a[3]);
    r[4] = f2bs(b[0]); r[5] = f2bs(b[1]); r[6] = f2bs(b[2]); r[7] = f2bs(b[3]);
    return r;
}

// ---------------------------------------------------------------------------
// QKV projection GEMM: D[t][o] = sum_c X[c][t] * W[o][c] + bias[o]
// fp32 inputs -> bf16 LDS tiles. Output token-major fp32 into ws.
// grid: (T/64, 1536/64, B), block 256 (4 waves). Tile 64x64, BK=32.
// ---------------------------------------------------------------------------
__global__ __launch_bounds__(256) void gemm_qkv(
    const float* __restrict__ x,
    const float* __restrict__ wq, const float* __restrict__ bq,
    const float* __restrict__ wk, const float* __restrict__ bk,
    const float* __restrict__ wv, const float* __restrict__ bv,
    float* __restrict__ qt, float* __restrict__ kt, float* __restrict__ vt)
{
    const int tt   = blockIdx.x * 64;          // token tile base
    const int ot   = blockIdx.y * 64;          // stacked output channel tile [0,1536)
    const int b    = blockIdx.z;
    const int proj = ot >> 9;                  // 0=q 1=k 2=v
    const int orow = ot & 511;                 // channel base within proj
    const int head = orow >> 6;

    const float* W    = (proj == 0) ? wq : (proj == 1) ? wk : wv;
    const float* bsel = (proj == 0) ? bq : (proj == 1) ? bk : bv;
    float*       osel = (proj == 0) ? qt : (proj == 1) ? kt : vt;

    const float* X = x + (size_t)b * DIM_ * T_;

    __shared__ __align__(16) short Ws[64 * LDSTR];  // [o][c]
    __shared__ __align__(16) short Xs[64 * LDSTR];  // [t][c] (transposed)

    const int tid  = threadIdx.x;
    const int lane = tid & 63;
    const int wid  = tid >> 6;

    // staging assignments
    const int wrow = tid >> 2;          // 0..63 (W row)
    const int wcq  = (tid & 3) * 8;     // k-chunk
    const int xc   = tid >> 3;          // 0..31 (X row = channel)
    const int xtq  = (tid & 7) * 8;     // token chunk

    f32x4 acc[4];
#pragma unroll
    for (int n = 0; n < 4; ++n) acc[n] = (f32x4){0.f, 0.f, 0.f, 0.f};

    for (int kk = 0; kk < DIM_; kk += 32) {
        // stage W tile [64][32]
        *(s16x8*)(&Ws[wrow * LDSTR + wcq]) =
            cvt8(W + (size_t)(orow + wrow) * DIM_ + kk + wcq);
        // stage X tile transposed -> Xs[t][c]
        s16x8 xv8 = cvt8(X + (size_t)(kk + xc) * T_ + tt + xtq);
#pragma unroll
        for (int e = 0; e < 8; ++e) Xs[(xtq + e) * LDSTR + xc] = xv8[e];
        __syncthreads();

        // fragments: A rows = tokens (wave's 16 rows), B rows (cols of D) = o
        s16x8 a = *(const s16x8*)(&Xs[(wid * 16 + (lane & 15)) * LDSTR + 8 * (lane >> 4)]);
#pragma unroll
        for (int n = 0; n < 4; ++n) {
            s16x8 bf = *(const s16x8*)(&Ws[(n * 16 + (lane & 15)) * LDSTR + 8 * (lane >> 4)]);
            acc[n] = __builtin_amdgcn_mfma_f32_16x16x32_bf16(a, bf, acc[n], 0, 0, 0);
        }
        __syncthreads();
    }

    // epilogue: D row = token, col = o. C/D map: col = lane&15, row = (lane>>4)*4+e
    float* obase = osel + (size_t)(b * HEADS_ + head) * T_ * HD_;
#pragma unroll
    for (int n = 0; n < 4; ++n) {
        const int d    = n * 16 + (lane & 15);                 // dim within head
        const float bi = bsel[orow + d];
#pragma unroll
        for (int e = 0; e < 4; ++e) {
            const int t = tt + wid * 16 + (lane >> 4) * 4 + e;
            obase[(size_t)t * HD_ + d] = acc[n][e] + bi;
        }
    }
}

// ---------------------------------------------------------------------------
// Output projection GEMM: D[o][t] = sum_c W[o][c] * AO_t[t][c] + bias[o]
// W fp32 -> bf16; AO token-major bf16 in ws (direct contiguous staging).
// Output channel-major FP32 (d_out). grid: (T/64, 512/64, B), block 256.
// ---------------------------------------------------------------------------
__global__ __launch_bounds__(256) void gemm_out(
    const bf16* __restrict__ ao,
    const float* __restrict__ wo, const float* __restrict__ bo,
    float* __restrict__ out)
{
    const int tt = blockIdx.x * 64;
    const int ot = blockIdx.y * 64;
    const int b  = blockIdx.z;

    const short* X = (const short*)ao + (size_t)b * T_ * DIM_;  // token-major [T][DIM]

    __shared__ __align__(16) short Ws[64 * LDSTR];  // [o][c]
    __shared__ __align__(16) short Xs[64 * LDSTR];  // [t][c]

    const int tid  = threadIdx.x;
    const int lane = tid & 63;
    const int wid  = tid >> 6;

    const int row = tid >> 2;          // 0..63
    const int cq  = (tid & 3) * 8;     // k-chunk

    f32x4 acc[4];
#pragma unroll
    for (int n = 0; n < 4; ++n) acc[n] = (f32x4){0.f, 0.f, 0.f, 0.f};

    for (int kk = 0; kk < DIM_; kk += 32) {
        *(s16x8*)(&Ws[row * LDSTR + cq]) =
            cvt8(wo + (size_t)(ot + row) * DIM_ + kk + cq);
        *(s16x8*)(&Xs[row * LDSTR + cq]) =
            *(const s16x8*)(X + (size_t)(tt + row) * DIM_ + kk + cq);
        __syncthreads();

        // A rows = o (wave's 16 rows), B cols = tokens
        s16x8 a = *(const s16x8*)(&Ws[(wid * 16 + (lane & 15)) * LDSTR + 8 * (lane >> 4)]);
#pragma unroll
        for (int n = 0; n < 4; ++n) {
            s16x8 bf = *(const s16x8*)(&Xs[(n * 16 + (lane & 15)) * LDSTR + 8 * (lane >> 4)]);
            acc[n] = __builtin_amdgcn_mfma_f32_16x16x32_bf16(a, bf, acc[n], 0, 0, 0);
        }
        __syncthreads();
    }

    float* obase = out + (size_t)b * DIM_ * T_;
#pragma unroll
    for (int n = 0; n < 4; ++n) {
        const int t = tt + n * 16 + (lane & 15);
#pragma unroll
        for (int e = 0; e < 4; ++e) {
            const int o    = ot + wid * 16 + (lane >> 4) * 4 + e;
            obase[(size_t)o * T_ + t] = acc[n][e] + bo[o];
        }
    }
}

// ---------------------------------------------------------------------------
// Neighborhood attention + self-value rejection, LDS-staged K.
// Block (4 waves) = 16 consecutive tokens in one image row of one (b,h).
// K window (7 x 22 = 154 rows, coords clamped) staged fp32 in LDS with a
// 16B-chunk rotate swizzle: logical chunk c of row w lives at chunk (c+w)&15.
// Phase 1: lane j = neighbor j; K row from LDS (read physical (c+rj)&15 ->
//          logical chunk c, paired with q chunk c).
// Phase 2: lane d = dim d; coalesced global V rows; p_j via readlane.
// Writes ao TOKEN-major bf16 [B][T][512].
// grid: B*H*(T/16) = 2304 blocks of 256.
// ---------------------------------------------------------------------------
__global__ __launch_bounds__(256) void attn_kernel(
    const float* __restrict__ qt, const float* __restrict__ kt,
    const float* __restrict__ vt, bf16* __restrict__ ao)
{
    __shared__ float Ks[WROWS * 64];   // 39424 B, row = 256B, swizzled chunks

    const int idx = blockIdx.x;
    const int bh  = idx / 144;               // (b*8+h)
    const int rem = idx - bh * 144;
    const int y   = rem / 3;
    const int x0  = (rem - y * 3) * 16;

    const float* qb = qt + (size_t)bh * T_ * HD_;
    const float* kb = kt + (size_t)bh * T_ * HD_;
    const float* vb = vt + (size_t)bh * T_ * HD_;

    const int tid  = threadIdx.x;
    const int lane = tid & 63;
    const int wid  = tid >> 6;

    // ---- stage K window: rows w = wy*22+wx, coords clamped ----
    {
        const int l16 = tid & 15;            // 16B chunk id (logical)
        const int r0  = tid >> 4;            // 0..15
#pragma unroll
        for (int p = 0; p < 10; ++p) {
            const int w = p * 16 + r0;
            if (w < WROWS) {
                const int wy = w / 22;
                const int wx = w - wy * 22;
                const int gy = min(max(y - R_ + wy, 0), Hh - 1);
                const int gx = min(max(x0 - R_ + wx, 0), Ww - 1);
                f32x4 v4 = *(const f32x4*)(kb + (size_t)(gy * Ww + gx) * HD_ + l16 * 4);
                *(f32x4*)(&Ks[w * 64 + ((l16 + w) & 15) * 4]) = v4;
            }
        }
    }
    __syncthreads();

    const int jy = (lane < KK_) ? lane / NS_ : 0;
    const int jx = (lane < KK_) ? lane - jy * NS_ : 0;

    // each wave handles 4 tokens sequentially: dx = wid*4 + ti
#pragma unroll
    for (int ti = 0; ti < 4; ++ti) {
        const int dx = wid * 4 + ti;
        const int x  = x0 + dx;
        const int t  = y * Ww + x;
        const float* qp = qb + (size_t)t * HD_;

        // ---- phase 1: scores (lane = neighbor), K from LDS ----
        float s = -3.0e38f;
        {
            const int ny = y + jy - R_;
            const int nx = x + jx - R_;
            const bool valid = (lane < KK_) & (ny >= 0) & (ny < Hh) & (nx >= 0) & (nx < Ww);
            const int  rj = jy * 22 + dx + jx;     // LDS window row
            float dot = 0.f;
#pragma unroll
            for (int c = 0; c < 16; ++c) {
                // physical chunk (c+rj)&15 holds LOGICAL chunk c of K row rj
                f32x4 k4 = *(const f32x4*)(&Ks[rj * 64 + ((c + rj) & 15) * 4]);
                f32x4 q4 = *(const f32x4*)(qp + c * 4);
                dot += q4[0]*k4[0] + q4[1]*k4[1] + q4[2]*k4[2] + q4[3]*k4[3];
            }
            s = valid ? dot * 0.125f : -3.0e38f;
        }

        // ---- wave softmax ----
        float m = s;
#pragma unroll
        for (int off = 32; off; off >>= 1) m = fmaxf(m, __shfl_xor(m, off));
        float p = __expf(s - m);
        float sum = p;
#pragma unroll
        for (int off = 32; off; off >>= 1) sum += __shfl_xor(sum, off);
        p *= 1.0f / sum;

        // ---- phase 2: PV (lane = dim) ----
        const int d = lane;
        float o_d = 0.f;
#pragma unroll
        for (int j = 0; j < KK_; ++j) {
            const int ny  = min(max(y + j / NS_ - R_, 0), Hh - 1);
            const int nx  = min(max(x + j % NS_ - R_, 0), Ww - 1);
            const float pj = __shfl(p, j);
            o_d += pj * vb[(size_t)(ny * Ww + nx) * HD_ + d];
        }

        // ---- self-value rejection ----
        const float vs = vb[(size_t)t * HD_ + d];
        float n2 = vs * vs;
#pragma unroll
        for (int off = 32; off; off >>= 1) n2 += __shfl_xor(n2, off);
        float odv = o_d * vs;
#pragma unroll
        for (int off = 32; off; off >>= 1) odv += __shfl_xor(odv, off);
        const float mx    = fmaxf(sqrtf(n2), 1e-12f);
        const float coeff = odv / (mx * mx);

        // ---- store token-major (coalesced 128B/wave) ----
        const int b = bh >> 3, h = bh & 7;
        ao[((size_t)b * T_ + t) * DIM_ + h * HD_ + d] = __float2bfloat16(o_d - coeff * vs);
    }
}

// ---------------------------------------------------------------------------
extern "C" void kernel_launch(void* const* d_in, const int* in_sizes, int n_in,
                              void* d_out, int out_size, void* d_ws, size_t ws_size,
                              hipStream_t stream)
{
    (void)in_sizes; (void)n_in; (void)out_size; (void)ws_size;

    const float* x  = (const float*)d_in[0];
    const float* wq = (const float*)d_in[1];
    const float* bq = (const float*)d_in[2];
    const float* wk = (const float*)d_in[3];
    const float* bk = (const float*)d_in[4];
    const float* wv = (const float*)d_in[5];
    const float* bv = (const float*)d_in[6];
    const float* wo = (const float*)d_in[7];
    const float* bo = (const float*)d_in[8];
    float* out = (float*)d_out;   // reference output dtype is float32

    // workspace layout (fp32 q,k,v token-major; bf16 ao token-major) ~33 MB
    const size_t per = (size_t)B_ * HEADS_ * T_ * HD_;   // 2359296
    float* qt = (float*)d_ws;
    float* kt = qt + per;
    float* vt = kt + per;
    bf16*  ao = (bf16*)(vt + per);

    dim3 g1(T_ / 64, 1536 / 64, B_);
    gemm_qkv<<<g1, 256, 0, stream>>>(x, wq, bq, wk, bk, wv, bv, qt, kt, vt);

    attn_kernel<<<dim3(B_ * HEADS_ * (T_ / 16)), 256, 0, stream>>>(qt, kt, vt, ao);

    dim3 g2(T_ / 64, DIM_ / 64, B_);
    gemm_out<<<g2, 256, 0, stream>>>(ao, wo, bo, out);
}

// Round 7
// 105.641 us; speedup vs baseline: 2.0378x; 1.1574x over previous
//
#include <hip/hip_runtime.h>
#include <hip/hip_bf16.h>
#include <math.h>

typedef __hip_bfloat16 bf16;
typedef __attribute__((ext_vector_type(4))) float f32x4;
typedef __attribute__((ext_vector_type(8))) short s16x8;

#define B_     2
#define DIM_   512
#define Hh     48
#define Ww     48
#define T_     2304
#define HEADS_ 8
#define HD_    64
#define NS_    7
#define R_     3
#define KK_    49

#define LDSTR  40   // padded LDS row stride (elems) for GEMM tiles
#define WROWS  154  // 7 * 22 neighborhood window rows for a 16-token chunk

__device__ __forceinline__ short f2bs(float f) {
    bf16 h = __float2bfloat16(f);
    return *(short*)&h;
}

// load 8 contiguous fp32, convert to 8 bf16 (as shorts)
__device__ __forceinline__ s16x8 cvt8(const float* __restrict__ p) {
    f32x4 a = *(const f32x4*)p;
    f32x4 b = *(const f32x4*)(p + 4);
    s16x8 r;
    r[0] = f2bs(a[0]); r[1] = f2bs(a[1]); r[2] = f2bs(a[2]); r[3] = f2bs(a[3]);
    r[4] = f2bs(b[0]); r[5] = f2bs(b[1]); r[6] = f2bs(b[2]); r[7] = f2bs(b[3]);
    return r;
}

// ---------------------------------------------------------------------------
// prep_xt: transpose-convert X [B][512][T] fp32 -> Xt [B][T][512] bf16.
// grid (T/64, DIM/64, B), block 256. LDS tile [64 t][72 c] (16B-aligned rows).
// ---------------------------------------------------------------------------
__global__ __launch_bounds__(256) void prep_xt(
    const float* __restrict__ x, bf16* __restrict__ xt)
{
    __shared__ short tile[64 * 72];   // [t][c]
    const int t0 = blockIdx.x * 64;
    const int c0 = blockIdx.y * 64;
    const int b  = blockIdx.z;
    const int tid = threadIdx.x;

    const float* X = x + (size_t)b * DIM_ * T_;

    const int c_l = tid >> 4;          // 0..15
    const int t4  = (tid & 15) * 4;    // 0..60
#pragma unroll
    for (int cp = 0; cp < 4; ++cp) {
        const int c = cp * 16 + c_l;
        f32x4 v = *(const f32x4*)(X + (size_t)(c0 + c) * T_ + t0 + t4);
#pragma unroll
        for (int e = 0; e < 4; ++e) tile[(t4 + e) * 72 + c] = f2bs(v[e]);
    }
    __syncthreads();

    const int t_l = tid >> 2;           // 0..63
    const int c16 = (tid & 3) * 16;     // 0,16,32,48
    short* dst = (short*)xt + ((size_t)b * T_ + t0 + t_l) * DIM_ + c0 + c16;
    *(s16x8*)(dst)     = *(const s16x8*)(&tile[t_l * 72 + c16]);
    *(s16x8*)(dst + 8) = *(const s16x8*)(&tile[t_l * 72 + c16 + 8]);
}

// ---------------------------------------------------------------------------
// QKV projection GEMM: D[t][o] = sum_c Xt[t][c] * W[o][c] + bias[o]
// A = Xt (token-major bf16, contiguous staging), B = W (fp32 -> cvt8).
// Tile 128(t) x 64(o), BK=32, 4 waves, 2 M-reps/wave. Output token-major fp32.
// grid: (T/128, 1536/64, B), block 256.
// ---------------------------------------------------------------------------
__global__ __launch_bounds__(256) void gemm_qkv(
    const bf16* __restrict__ xt,
    const float* __restrict__ wq, const float* __restrict__ bq,
    const float* __restrict__ wk, const float* __restrict__ bk,
    const float* __restrict__ wv, const float* __restrict__ bv,
    float* __restrict__ qt, float* __restrict__ kt, float* __restrict__ vt)
{
    const int tt   = blockIdx.x * 128;         // token tile base
    const int ot   = blockIdx.y * 64;          // stacked output channel tile [0,1536)
    const int b    = blockIdx.z;
    const int proj = ot >> 9;                  // 0=q 1=k 2=v
    const int orow = ot & 511;                 // channel base within proj
    const int head = orow >> 6;

    const float* W    = (proj == 0) ? wq : (proj == 1) ? wk : wv;
    const float* bsel = (proj == 0) ? bq : (proj == 1) ? bk : bv;
    float*       osel = (proj == 0) ? qt : (proj == 1) ? kt : vt;

    const short* X = (const short*)xt + (size_t)b * T_ * DIM_;  // [T][512]

    __shared__ __align__(16) short Xs[128 * LDSTR];  // [t][c]
    __shared__ __align__(16) short Ws[64 * LDSTR];   // [o][c]

    const int tid  = threadIdx.x;
    const int lane = tid & 63;
    const int wid  = tid >> 6;

    const int row = tid >> 2;          // 0..63
    const int cq  = (tid & 3) * 8;     // k-chunk

    f32x4 acc[2][4];
#pragma unroll
    for (int r = 0; r < 2; ++r)
#pragma unroll
        for (int n = 0; n < 4; ++n) acc[r][n] = (f32x4){0.f, 0.f, 0.f, 0.f};

    for (int kk = 0; kk < DIM_; kk += 32) {
#pragma unroll
        for (int rr = 0; rr < 2; ++rr)
            *(s16x8*)(&Xs[(rr * 64 + row) * LDSTR + cq]) =
                *(const s16x8*)(X + (size_t)(tt + rr * 64 + row) * DIM_ + kk + cq);
        *(s16x8*)(&Ws[row * LDSTR + cq]) =
            cvt8(W + (size_t)(orow + row) * DIM_ + kk + cq);
        __syncthreads();

        s16x8 a[2];
#pragma unroll
        for (int r = 0; r < 2; ++r)
            a[r] = *(const s16x8*)(&Xs[(r * 64 + wid * 16 + (lane & 15)) * LDSTR + 8 * (lane >> 4)]);
#pragma unroll
        for (int n = 0; n < 4; ++n) {
            s16x8 bf = *(const s16x8*)(&Ws[(n * 16 + (lane & 15)) * LDSTR + 8 * (lane >> 4)]);
#pragma unroll
            for (int r = 0; r < 2; ++r)
                acc[r][n] = __builtin_amdgcn_mfma_f32_16x16x32_bf16(a[r], bf, acc[r][n], 0, 0, 0);
        }
        __syncthreads();
    }

    // epilogue: D row = token, col = o. C/D map: col = lane&15, row = (lane>>4)*4+e
    float* obase = osel + (size_t)(b * HEADS_ + head) * T_ * HD_;
#pragma unroll
    for (int r = 0; r < 2; ++r)
#pragma unroll
        for (int n = 0; n < 4; ++n) {
            const int d    = n * 16 + (lane & 15);             // dim within head
            const float bi = bsel[orow + d];
#pragma unroll
            for (int e = 0; e < 4; ++e) {
                const int t = tt + r * 64 + wid * 16 + (lane >> 4) * 4 + e;
                obase[(size_t)t * HD_ + d] = acc[r][n][e] + bi;
            }
        }
}

// ---------------------------------------------------------------------------
// Output projection GEMM: D[o][t] = sum_c W[o][c] * AO_t[t][c] + bias[o]
// W fp32 -> bf16; AO token-major bf16 in ws. Output channel-major FP32.
// grid: (T/64, 512/64, B), block 256.
// ---------------------------------------------------------------------------
__global__ __launch_bounds__(256) void gemm_out(
    const bf16* __restrict__ ao,
    const float* __restrict__ wo, const float* __restrict__ bo,
    float* __restrict__ out)
{
    const int tt = blockIdx.x * 64;
    const int ot = blockIdx.y * 64;
    const int b  = blockIdx.z;

    const short* X = (const short*)ao + (size_t)b * T_ * DIM_;  // token-major [T][DIM]

    __shared__ __align__(16) short Ws[64 * LDSTR];  // [o][c]
    __shared__ __align__(16) short Xs[64 * LDSTR];  // [t][c]

    const int tid  = threadIdx.x;
    const int lane = tid & 63;
    const int wid  = tid >> 6;

    const int row = tid >> 2;          // 0..63
    const int cq  = (tid & 3) * 8;     // k-chunk

    f32x4 acc[4];
#pragma unroll
    for (int n = 0; n < 4; ++n) acc[n] = (f32x4){0.f, 0.f, 0.f, 0.f};

    for (int kk = 0; kk < DIM_; kk += 32) {
        *(s16x8*)(&Ws[row * LDSTR + cq]) =
            cvt8(wo + (size_t)(ot + row) * DIM_ + kk + cq);
        *(s16x8*)(&Xs[row * LDSTR + cq]) =
            *(const s16x8*)(X + (size_t)(tt + row) * DIM_ + kk + cq);
        __syncthreads();

        // A rows = o (wave's 16 rows), B cols = tokens
        s16x8 a = *(const s16x8*)(&Ws[(wid * 16 + (lane & 15)) * LDSTR + 8 * (lane >> 4)]);
#pragma unroll
        for (int n = 0; n < 4; ++n) {
            s16x8 bf = *(const s16x8*)(&Xs[(n * 16 + (lane & 15)) * LDSTR + 8 * (lane >> 4)]);
            acc[n] = __builtin_amdgcn_mfma_f32_16x16x32_bf16(a, bf, acc[n], 0, 0, 0);
        }
        __syncthreads();
    }

    float* obase = out + (size_t)b * DIM_ * T_;
#pragma unroll
    for (int n = 0; n < 4; ++n) {
        const int t = tt + n * 16 + (lane & 15);
#pragma unroll
        for (int e = 0; e < 4; ++e) {
            const int o    = ot + wid * 16 + (lane >> 4) * 4 + e;
            obase[(size_t)o * T_ + t] = acc[n][e] + bo[o];
        }
    }
}

// ---------------------------------------------------------------------------
// Neighborhood attention + self-value rejection, K AND V LDS-staged.
// Block = 1024 threads = 16 waves = 16 consecutive tokens in one image row.
// Pass 1: stage K window (154 rows) with 16B-chunk rotate swizzle; phase 1
//         (lane j = neighbor): dot from LDS. Pass 2 (same buffer): stage V
//         unswizzled; phase 2 (lane d = dim): ds_read at const row offsets.
// Self-V read from LDS window row 69+wid. Writes ao TOKEN-major bf16.
// grid: B*H*(T/16) = 2304 blocks of 1024.
// ---------------------------------------------------------------------------
__global__ __launch_bounds__(1024) void attn_kernel(
    const float* __restrict__ qt, const float* __restrict__ kt,
    const float* __restrict__ vt, bf16* __restrict__ ao)
{
    __shared__ float KV[WROWS * 64];   // 39424 B

    const int idx = blockIdx.x;
    const int bh  = idx / 144;               // (b*8+h)
    const int rem = idx - bh * 144;
    const int y   = rem / 3;
    const int x0  = (rem - y * 3) * 16;

    const float* qb = qt + (size_t)bh * T_ * HD_;
    const float* kb = kt + (size_t)bh * T_ * HD_;
    const float* vb = vt + (size_t)bh * T_ * HD_;

    const int tid  = threadIdx.x;
    const int lane = tid & 63;
    const int wid  = tid >> 6;               // 0..15 = token within chunk

    const int l16 = tid & 15;                // 16B chunk id (logical)
    const int r0  = tid >> 4;                // 0..63

    // ---- pass 1: stage K window, chunk-rotate swizzled ----
#pragma unroll
    for (int p = 0; p < 3; ++p) {
        const int w = p * 64 + r0;
        if (w < WROWS) {
            const int wy = w / 22;
            const int wx = w - wy * 22;
            const int gy = min(max(y - R_ + wy, 0), Hh - 1);
            const int gx = min(max(x0 - R_ + wx, 0), Ww - 1);
            f32x4 v4 = *(const f32x4*)(kb + (size_t)(gy * Ww + gx) * HD_ + l16 * 4);
            *(f32x4*)(&KV[w * 64 + ((l16 + w) & 15) * 4]) = v4;
        }
    }
    __syncthreads();

    const int jy = (lane < KK_) ? lane / NS_ : 0;
    const int jx = (lane < KK_) ? lane - jy * NS_ : 0;

    const int x = x0 + wid;
    const int t = y * Ww + x;
    const float* qp = qb + (size_t)t * HD_;

    // ---- phase 1: scores (lane = neighbor), K from LDS ----
    float s = -3.0e38f;
    {
        const int ny = y + jy - R_;
        const int nx = x + jx - R_;
        const bool valid = (lane < KK_) & (ny >= 0) & (ny < Hh) & (nx >= 0) & (nx < Ww);
        const int  rj = jy * 22 + wid + jx;     // LDS window row
        float dot = 0.f;
#pragma unroll
        for (int c = 0; c < 16; ++c) {
            // physical chunk (c+rj)&15 holds LOGICAL chunk c of K row rj
            f32x4 k4 = *(const f32x4*)(&KV[rj * 64 + ((c + rj) & 15) * 4]);
            f32x4 q4 = *(const f32x4*)(qp + c * 4);
            dot += q4[0]*k4[0] + q4[1]*k4[1] + q4[2]*k4[2] + q4[3]*k4[3];
        }
        s = valid ? dot * 0.125f : -3.0e38f;
    }

    // ---- wave softmax ----
    float m = s;
#pragma unroll
    for (int off = 32; off; off >>= 1) m = fmaxf(m, __shfl_xor(m, off));
    float p = __expf(s - m);
    float sum = p;
#pragma unroll
    for (int off = 32; off; off >>= 1) sum += __shfl_xor(sum, off);
    p *= 1.0f / sum;

    __syncthreads();   // all phase-1 LDS reads done before overwrite

    // ---- pass 2: stage V window, unswizzled ----
#pragma unroll
    for (int pp = 0; pp < 3; ++pp) {
        const int w = pp * 64 + r0;
        if (w < WROWS) {
            const int wy = w / 22;
            const int wx = w - wy * 22;
            const int gy = min(max(y - R_ + wy, 0), Hh - 1);
            const int gx = min(max(x0 - R_ + wx, 0), Ww - 1);
            f32x4 v4 = *(const f32x4*)(vb + (size_t)(gy * Ww + gx) * HD_ + l16 * 4);
            *(f32x4*)(&KV[w * 64 + l16 * 4]) = v4;
        }
    }
    __syncthreads();

    // ---- phase 2: PV (lane = dim), V from LDS at const row offsets ----
    const int d = lane;
    float o_d = 0.f;
#pragma unroll
    for (int j = 0; j < KK_; ++j) {
        const int Cj = (j / NS_) * 22 + (j % NS_);   // compile-time
        const float pj = __shfl(p, j);
        o_d += pj * KV[(Cj + wid) * 64 + d];
    }

    // ---- self-value rejection (self row = 69 + wid) ----
    const float vs = KV[(69 + wid) * 64 + d];
    float n2 = vs * vs;
#pragma unroll
    for (int off = 32; off; off >>= 1) n2 += __shfl_xor(n2, off);
    float odv = o_d * vs;
#pragma unroll
    for (int off = 32; off; off >>= 1) odv += __shfl_xor(odv, off);
    const float mx    = fmaxf(sqrtf(n2), 1e-12f);
    const float coeff = odv / (mx * mx);

    // ---- store token-major (coalesced 128B/wave) ----
    const int b = bh >> 3, h = bh & 7;
    ao[((size_t)b * T_ + t) * DIM_ + h * HD_ + d] = __float2bfloat16(o_d - coeff * vs);
}

// ---------------------------------------------------------------------------
extern "C" void kernel_launch(void* const* d_in, const int* in_sizes, int n_in,
                              void* d_out, int out_size, void* d_ws, size_t ws_size,
                              hipStream_t stream)
{
    (void)in_sizes; (void)n_in; (void)out_size; (void)ws_size;

    const float* x  = (const float*)d_in[0];
    const float* wq = (const float*)d_in[1];
    const float* bq = (const float*)d_in[2];
    const float* wk = (const float*)d_in[3];
    const float* bk = (const float*)d_in[4];
    const float* wv = (const float*)d_in[5];
    const float* bv = (const float*)d_in[6];
    const float* wo = (const float*)d_in[7];
    const float* bo = (const float*)d_in[8];
    float* out = (float*)d_out;   // reference output dtype is float32

    // workspace: fp32 q,k,v token-major (28.3 MB) + bf16 buffer (4.7 MB)
    // shared by Xt (prep->gemm_qkv) then ao (attn->gemm_out): stream-ordered.
    const size_t per = (size_t)B_ * HEADS_ * T_ * HD_;   // 2359296
    float* qt = (float*)d_ws;
    float* kt = qt + per;
    float* vt = kt + per;
    bf16*  xa = (bf16*)(vt + per);    // Xt, later overwritten by ao

    prep_xt<<<dim3(T_ / 64, DIM_ / 64, B_), 256, 0, stream>>>(x, xa);

    dim3 g1(T_ / 128, 1536 / 64, B_);
    gemm_qkv<<<g1, 256, 0, stream>>>(xa, wq, bq, wk, bk, wv, bv, qt, kt, vt);

    attn_kernel<<<dim3(B_ * HEADS_ * (T_ / 16)), 1024, 0, stream>>>(qt, kt, vt, xa);

    dim3 g2(T_ / 64, DIM_ / 64, B_);
    gemm_out<<<g2, 256, 0, stream>>>(xa, wo, bo, out);
}

// Round 8
// 97.866 us; speedup vs baseline: 2.1997x; 1.0794x over previous
//
#include <hip/hip_runtime.h>
#include <hip/hip_bf16.h>
#include <math.h>

typedef __hip_bfloat16 bf16;
typedef __attribute__((ext_vector_type(4))) float f32x4;
typedef __attribute__((ext_vector_type(8))) short s16x8;

#define B_     2
#define DIM_   512
#define Hh     48
#define Ww     48
#define T_     2304
#define HEADS_ 8
#define HD_    64
#define NS_    7
#define R_     3
#define KK_    49

#define LDSTR  40   // padded LDS row stride (elems) for GEMM tiles

__device__ __forceinline__ short f2bs(float f) {
    bf16 h = __float2bfloat16(f);
    return *(short*)&h;
}

// load 8 contiguous fp32, convert to 8 bf16 (as shorts)
__device__ __forceinline__ s16x8 cvt8(const float* __restrict__ p) {
    f32x4 a = *(const f32x4*)p;
    f32x4 b = *(const f32x4*)(p + 4);
    s16x8 r;
    r[0] = f2bs(a[0]); r[1] = f2bs(a[1]); r[2] = f2bs(a[2]); r[3] = f2bs(a[3]);
    r[4] = f2bs(b[0]); r[5] = f2bs(b[1]); r[6] = f2bs(b[2]); r[7] = f2bs(b[3]);
    return r;
}

// ---------------------------------------------------------------------------
// prep_xt: transpose-convert X [B][512][T] fp32 -> Xt [B][T][512] bf16.
// ---------------------------------------------------------------------------
__global__ __launch_bounds__(256) void prep_xt(
    const float* __restrict__ x, bf16* __restrict__ xt)
{
    __shared__ short tile[64 * 72];   // [t][c]
    const int t0 = blockIdx.x * 64;
    const int c0 = blockIdx.y * 64;
    const int b  = blockIdx.z;
    const int tid = threadIdx.x;

    const float* X = x + (size_t)b * DIM_ * T_;

    const int c_l = tid >> 4;          // 0..15
    const int t4  = (tid & 15) * 4;    // 0..60
#pragma unroll
    for (int cp = 0; cp < 4; ++cp) {
        const int c = cp * 16 + c_l;
        f32x4 v = *(const f32x4*)(X + (size_t)(c0 + c) * T_ + t0 + t4);
#pragma unroll
        for (int e = 0; e < 4; ++e) tile[(t4 + e) * 72 + c] = f2bs(v[e]);
    }
    __syncthreads();

    const int t_l = tid >> 2;           // 0..63
    const int c16 = (tid & 3) * 16;     // 0,16,32,48
    short* dst = (short*)xt + ((size_t)b * T_ + t0 + t_l) * DIM_ + c0 + c16;
    *(s16x8*)(dst)     = *(const s16x8*)(&tile[t_l * 72 + c16]);
    *(s16x8*)(dst + 8) = *(const s16x8*)(&tile[t_l * 72 + c16 + 8]);
}

// ---------------------------------------------------------------------------
// QKV projection GEMM: D[t][o] = sum_c Xt[t][c] * W[o][c] + bias[o]
// Tile 128(t) x 64(o), BK=32, 4 waves. Output token-major fp32.
// ---------------------------------------------------------------------------
__global__ __launch_bounds__(256) void gemm_qkv(
    const bf16* __restrict__ xt,
    const float* __restrict__ wq, const float* __restrict__ bq,
    const float* __restrict__ wk, const float* __restrict__ bk,
    const float* __restrict__ wv, const float* __restrict__ bv,
    float* __restrict__ qt, float* __restrict__ kt, float* __restrict__ vt)
{
    const int tt   = blockIdx.x * 128;
    const int ot   = blockIdx.y * 64;
    const int b    = blockIdx.z;
    const int proj = ot >> 9;
    const int orow = ot & 511;
    const int head = orow >> 6;

    const float* W    = (proj == 0) ? wq : (proj == 1) ? wk : wv;
    const float* bsel = (proj == 0) ? bq : (proj == 1) ? bk : bv;
    float*       osel = (proj == 0) ? qt : (proj == 1) ? kt : vt;

    const short* X = (const short*)xt + (size_t)b * T_ * DIM_;

    __shared__ __align__(16) short Xs[128 * LDSTR];
    __shared__ __align__(16) short Ws[64 * LDSTR];

    const int tid  = threadIdx.x;
    const int lane = tid & 63;
    const int wid  = tid >> 6;

    const int row = tid >> 2;
    const int cq  = (tid & 3) * 8;

    f32x4 acc[2][4];
#pragma unroll
    for (int r = 0; r < 2; ++r)
#pragma unroll
        for (int n = 0; n < 4; ++n) acc[r][n] = (f32x4){0.f, 0.f, 0.f, 0.f};

    for (int kk = 0; kk < DIM_; kk += 32) {
#pragma unroll
        for (int rr = 0; rr < 2; ++rr)
            *(s16x8*)(&Xs[(rr * 64 + row) * LDSTR + cq]) =
                *(const s16x8*)(X + (size_t)(tt + rr * 64 + row) * DIM_ + kk + cq);
        *(s16x8*)(&Ws[row * LDSTR + cq]) =
            cvt8(W + (size_t)(orow + row) * DIM_ + kk + cq);
        __syncthreads();

        s16x8 a[2];
#pragma unroll
        for (int r = 0; r < 2; ++r)
            a[r] = *(const s16x8*)(&Xs[(r * 64 + wid * 16 + (lane & 15)) * LDSTR + 8 * (lane >> 4)]);
#pragma unroll
        for (int n = 0; n < 4; ++n) {
            s16x8 bf = *(const s16x8*)(&Ws[(n * 16 + (lane & 15)) * LDSTR + 8 * (lane >> 4)]);
#pragma unroll
            for (int r = 0; r < 2; ++r)
                acc[r][n] = __builtin_amdgcn_mfma_f32_16x16x32_bf16(a[r], bf, acc[r][n], 0, 0, 0);
        }
        __syncthreads();
    }

    float* obase = osel + (size_t)(b * HEADS_ + head) * T_ * HD_;
#pragma unroll
    for (int r = 0; r < 2; ++r)
#pragma unroll
        for (int n = 0; n < 4; ++n) {
            const int d    = n * 16 + (lane & 15);
            const float bi = bsel[orow + d];
#pragma unroll
            for (int e = 0; e < 4; ++e) {
                const int t = tt + r * 64 + wid * 16 + (lane >> 4) * 4 + e;
                obase[(size_t)t * HD_ + d] = acc[r][n][e] + bi;
            }
        }
}

// ---------------------------------------------------------------------------
// Output projection GEMM (unchanged).
// ---------------------------------------------------------------------------
__global__ __launch_bounds__(256) void gemm_out(
    const bf16* __restrict__ ao,
    const float* __restrict__ wo, const float* __restrict__ bo,
    float* __restrict__ out)
{
    const int tt = blockIdx.x * 64;
    const int ot = blockIdx.y * 64;
    const int b  = blockIdx.z;

    const short* X = (const short*)ao + (size_t)b * T_ * DIM_;

    __shared__ __align__(16) short Ws[64 * LDSTR];
    __shared__ __align__(16) short Xs[64 * LDSTR];

    const int tid  = threadIdx.x;
    const int lane = tid & 63;
    const int wid  = tid >> 6;

    const int row = tid >> 2;
    const int cq  = (tid & 3) * 8;

    f32x4 acc[4];
#pragma unroll
    for (int n = 0; n < 4; ++n) acc[n] = (f32x4){0.f, 0.f, 0.f, 0.f};

    for (int kk = 0; kk < DIM_; kk += 32) {
        *(s16x8*)(&Ws[row * LDSTR + cq]) =
            cvt8(wo + (size_t)(ot + row) * DIM_ + kk + cq);
        *(s16x8*)(&Xs[row * LDSTR + cq]) =
            *(const s16x8*)(X + (size_t)(tt + row) * DIM_ + kk + cq);
        __syncthreads();

        s16x8 a = *(const s16x8*)(&Ws[(wid * 16 + (lane & 15)) * LDSTR + 8 * (lane >> 4)]);
#pragma unroll
        for (int n = 0; n < 4; ++n) {
            s16x8 bf = *(const s16x8*)(&Xs[(n * 16 + (lane & 15)) * LDSTR + 8 * (lane >> 4)]);
            acc[n] = __builtin_amdgcn_mfma_f32_16x16x32_bf16(a, bf, acc[n], 0, 0, 0);
        }
        __syncthreads();
    }

    float* obase = out + (size_t)b * DIM_ * T_;
#pragma unroll
    for (int n = 0; n < 4; ++n) {
        const int t = tt + n * 16 + (lane & 15);
#pragma unroll
        for (int e = 0; e < 4; ++e) {
            const int o    = ot + wid * 16 + (lane >> 4) * 4 + e;
            obase[(size_t)o * T_ + t] = acc[n][e] + bo[o];
        }
    }
}

// ---------------------------------------------------------------------------
// MFMA neighborhood attention. Block = (b,h) x 16-token chunk, 4 waves.
// w-space: w = wy*24 + u (u<22 real, wy<7); real w <= 165, S^T over 11
// m-tiles (w<176), PV over K=192 (pads zeroed).
// S^T[w][t] = Kl(A) x Ql(B); softmax wave-local (all waves compute all
// m-tiles); P->LDS bf16; O[t][d] = Pl(A) x VT(B). fp32 v_s for rejection.
// grid: 2304 blocks of 256, XCD-swizzled.
// ---------------------------------------------------------------------------
__global__ __launch_bounds__(256, 2) void attn_mfma(
    const float* __restrict__ qt, const float* __restrict__ kt,
    const float* __restrict__ vt, bf16* __restrict__ ao)
{
    __shared__ __align__(16) char smem[59648];
    short* Kl = (short*)smem;                            // [176][72]
    short* Ql = (short*)(smem + 25344);                  // [16][72]
    short* VT = (short*)(smem + 25344 + 2304);           // [64][200]
    short* Pl = (short*)(smem + 25344 + 2304 + 25600);   // [16][200]
    float* Ol = (float*)smem;                            // [16][72] alias on Kl

    const int l   = blockIdx.x;
    const int idx = (l & 7) * 288 + (l >> 3);            // XCD-contiguous work
    const int bh  = idx / 144;
    const int rem = idx - bh * 144;
    const int y   = rem / 3;
    const int x0  = (rem % 3) * 16;

    const float* qb = qt + (size_t)bh * T_ * HD_;
    const float* kb = kt + (size_t)bh * T_ * HD_;
    const float* vb = vt + (size_t)bh * T_ * HD_;

    const int tid  = threadIdx.x;
    const int lane = tid & 63;
    const int wv   = tid >> 6;
    const int qq   = lane >> 4;
    const int ln   = lane & 15;

    // ---- stage K rows (bf16), w = wy*24+u ----
    {
        const int c8 = (tid & 7) * 8;
        const int wr = tid >> 3;           // 0..31
#pragma unroll
        for (int p = 0; p < 6; ++p) {
            const int w = p * 32 + wr;
            if (w < 168) {
                const int wy = w / 24, u = w - wy * 24;
                if (u < 22) {
                    const int gy = min(max(y + wy - 3, 0), 47);
                    const int gx = min(max(x0 + u - 3, 0), 47);
                    *(s16x8*)&Kl[w * 72 + c8] =
                        cvt8(kb + (size_t)(gy * 48 + gx) * 64 + c8);
                }
            }
        }
    }
    // ---- stage Q ----
    if (tid < 128) {
        const int t = tid >> 3, c8 = (tid & 7) * 8;
        *(s16x8*)&Ql[t * 72 + c8] = cvt8(qb + (size_t)(y * 48 + x0 + t) * 64 + c8);
    }
    // ---- zero VT pads: w in [168,200) and u-pads {22,23} per wy ----
    {
        const int d = tid >> 2, c = tid & 3;
        *(s16x8*)&VT[d * 200 + 168 + c * 8] = (s16x8){0,0,0,0,0,0,0,0};
    }
#pragma unroll
    for (int pp = 0; pp < 2; ++pp) {
        const int r = pp * 256 + tid;
        if (r < 448) {
            const int wy = r >> 6, d = r & 63;
            *(unsigned*)&VT[d * 200 + wy * 24 + 22] = 0u;
        }
    }
    // ---- zero Pl pads: w in [176,192) ----
    if (tid < 32) {
        const int t = tid >> 1, c = tid & 1;
        *(s16x8*)&Pl[t * 200 + 176 + c * 8] = (s16x8){0,0,0,0,0,0,0,0};
    }
    // ---- stage V transposed: VT[d][w] (e-rotated scatter) ----
    {
        const int rr0 = tid >> 4;          // 0..15
        const int d4  = (tid & 15) * 4;
        const int rot = tid & 3;
#pragma unroll
        for (int p = 0; p < 10; ++p) {
            const int rr = p * 16 + rr0;
            if (rr < 154) {
                const int wy = rr / 22, u = rr - wy * 22;
                const int w  = wy * 24 + u;
                const int gy = min(max(y + wy - 3, 0), 47);
                const int gx = min(max(x0 + u - 3, 0), 47);
                f32x4 v4 = *(const f32x4*)(vb + (size_t)(gy * 48 + gx) * 64 + d4);
#pragma unroll
                for (int e = 0; e < 4; ++e) {
                    const int ee = (e + rot) & 3;
                    VT[(d4 + ee) * 200 + w] = f2bs(v4[ee]);
                }
            }
        }
    }
    __syncthreads();

    // ---- S^T = K x Q^T: 11 m-tiles, 2 k-steps; ALL waves compute all ----
    f32x4 acc[11];
#pragma unroll
    for (int mt = 0; mt < 11; ++mt) acc[mt] = (f32x4){0.f, 0.f, 0.f, 0.f};
#pragma unroll
    for (int ks = 0; ks < 2; ++ks) {
        s16x8 bq_ = *(const s16x8*)&Ql[ln * 72 + ks * 32 + qq * 8];
#pragma unroll
        for (int mt = 0; mt < 11; ++mt) {
            s16x8 ak = *(const s16x8*)&Kl[(mt * 16 + ln) * 72 + ks * 32 + qq * 8];
            acc[mt] = __builtin_amdgcn_mfma_f32_16x16x32_bf16(ak, bq_, acc[mt], 0, 0, 0);
        }
    }

    // ---- mask + wave-local softmax (t = ln; w = mt*16 + qq*4 + e) ----
    const int dx = ln;
    float mxv = -3.0e38f;
#pragma unroll
    for (int mt = 0; mt < 11; ++mt) {
#pragma unroll
        for (int e = 0; e < 4; ++e) {
            const int w  = mt * 16 + qq * 4 + e;
            const int wy = w / 24, u = w - wy * 24;
            const bool valid = (w < 168) &&
                               ((unsigned)(u - dx) <= 6u) &&
                               ((unsigned)(y + wy - 3) < 48u) &&
                               ((unsigned)(x0 + u - 3) < 48u);
            const float s = valid ? acc[mt][e] * 0.125f : -3.0e38f;
            acc[mt][e] = s;
            mxv = fmaxf(mxv, s);
        }
    }
    mxv = fmaxf(mxv, __shfl_xor(mxv, 16));
    mxv = fmaxf(mxv, __shfl_xor(mxv, 32));
    float sum = 0.f;
#pragma unroll
    for (int mt = 0; mt < 11; ++mt)
#pragma unroll
        for (int e = 0; e < 4; ++e) {
            const float p = __expf(acc[mt][e] - mxv);
            acc[mt][e] = p;
            sum += p;
        }
    sum += __shfl_xor(sum, 16);
    sum += __shfl_xor(sum, 32);
    const float inv = 1.0f / sum;

    // ---- write P (wave-owned m-tiles) ----
#pragma unroll
    for (int mo = 0; mo < 3; ++mo) {
        const int mt = wv * 3 + mo;
        if (mt < 11) {
#pragma unroll
            for (int e = 0; e < 4; ++e) {
                const int w = mt * 16 + qq * 4 + e;
                Pl[ln * 200 + w] = f2bs(acc[mt][e] * inv);
            }
        }
    }
    __syncthreads();

    // ---- O = P x V: one 16-d n-tile per wave, K = 192 ----
    f32x4 oacc = (f32x4){0.f, 0.f, 0.f, 0.f};
#pragma unroll
    for (int ks = 0; ks < 6; ++ks) {
        s16x8 ap  = *(const s16x8*)&Pl[ln * 200 + ks * 32 + qq * 8];
        s16x8 bv_ = *(const s16x8*)&VT[(wv * 16 + ln) * 200 + ks * 32 + qq * 8];
        oacc = __builtin_amdgcn_mfma_f32_16x16x32_bf16(ap, bv_, oacc, 0, 0, 0);
    }
#pragma unroll
    for (int e = 0; e < 4; ++e)
        Ol[(qq * 4 + e) * 72 + wv * 16 + ln] = oacc[e];
    __syncthreads();

    // ---- self-value rejection (fp32 v from global) + store ----
    {
        const int tt = tid >> 4;       // token 0..15
        const int dl = tid & 15;
        const int tg = y * 48 + x0 + tt;
        const float o0 = Ol[tt * 72 + dl],      o1 = Ol[tt * 72 + dl + 16],
                    o2 = Ol[tt * 72 + dl + 32], o3 = Ol[tt * 72 + dl + 48];
        const float* vs = vb + (size_t)tg * 64 + dl;
        const float v0 = vs[0], v1 = vs[16], v2 = vs[32], v3 = vs[48];
        float n2  = v0 * v0 + v1 * v1 + v2 * v2 + v3 * v3;
        float odv = o0 * v0 + o1 * v1 + o2 * v2 + o3 * v3;
#pragma unroll
        for (int off = 1; off < 16; off <<= 1) {
            n2  += __shfl_xor(n2, off);
            odv += __shfl_xor(odv, off);
        }
        const float mxn = fmaxf(sqrtf(n2), 1e-12f);
        const float cf  = odv / (mxn * mxn);
        const int b = bh >> 3, h = bh & 7;
        bf16* dst = ao + ((size_t)b * T_ + tg) * DIM_ + h * 64 + dl;
        dst[0]  = __float2bfloat16(o0 - cf * v0);
        dst[16] = __float2bfloat16(o1 - cf * v1);
        dst[32] = __float2bfloat16(o2 - cf * v2);
        dst[48] = __float2bfloat16(o3 - cf * v3);
    }
}

// ---------------------------------------------------------------------------
extern "C" void kernel_launch(void* const* d_in, const int* in_sizes, int n_in,
                              void* d_out, int out_size, void* d_ws, size_t ws_size,
                              hipStream_t stream)
{
    (void)in_sizes; (void)n_in; (void)out_size; (void)ws_size;

    const float* x  = (const float*)d_in[0];
    const float* wq = (const float*)d_in[1];
    const float* bq = (const float*)d_in[2];
    const float* wk = (const float*)d_in[3];
    const float* bk = (const float*)d_in[4];
    const float* wv = (const float*)d_in[5];
    const float* bv = (const float*)d_in[6];
    const float* wo = (const float*)d_in[7];
    const float* bo = (const float*)d_in[8];
    float* out = (float*)d_out;

    // ws: fp32 q,k,v token-major (28.3 MB) + bf16 Xt/ao buffer (4.7 MB)
    const size_t per = (size_t)B_ * HEADS_ * T_ * HD_;   // 2359296
    float* qt = (float*)d_ws;
    float* kt = qt + per;
    float* vt = kt + per;
    bf16*  xa = (bf16*)(vt + per);    // Xt, later overwritten by ao

    prep_xt<<<dim3(T_ / 64, DIM_ / 64, B_), 256, 0, stream>>>(x, xa);

    dim3 g1(T_ / 128, 1536 / 64, B_);
    gemm_qkv<<<g1, 256, 0, stream>>>(xa, wq, bq, wk, bk, wv, bv, qt, kt, vt);

    attn_mfma<<<dim3(B_ * HEADS_ * (T_ / 16)), 256, 0, stream>>>(qt, kt, vt, xa);

    dim3 g2(T_ / 64, DIM_ / 64, B_);
    gemm_out<<<g2, 256, 0, stream>>>(xa, wo, bo, out);
}

// Round 9
// 84.709 us; speedup vs baseline: 2.5413x; 1.1553x over previous
//
#include <hip/hip_runtime.h>
#include <hip/hip_bf16.h>
#include <math.h>

typedef __hip_bfloat16 bf16;
typedef __attribute__((ext_vector_type(4))) float f32x4;
typedef __attribute__((ext_vector_type(8))) short s16x8;

#define B_     2
#define DIM_   512
#define Hh     48
#define Ww     48
#define T_     2304
#define HEADS_ 8
#define HD_    64
#define NS_    7
#define R_     3
#define KK_    49

#define LDSTR  40   // padded LDS row stride (elems) for GEMM tiles

__device__ __forceinline__ short f2bs(float f) {
    bf16 h = __float2bfloat16(f);
    return *(short*)&h;
}

// load 8 contiguous fp32, convert to 8 bf16 (as shorts)
__device__ __forceinline__ s16x8 cvt8(const float* __restrict__ p) {
    f32x4 a = *(const f32x4*)p;
    f32x4 b = *(const f32x4*)(p + 4);
    s16x8 r;
    r[0] = f2bs(a[0]); r[1] = f2bs(a[1]); r[2] = f2bs(a[2]); r[3] = f2bs(a[3]);
    r[4] = f2bs(b[0]); r[5] = f2bs(b[1]); r[6] = f2bs(b[2]); r[7] = f2bs(b[3]);
    return r;
}

// ---------------------------------------------------------------------------
// prep_xt: transpose-convert X [B][512][T] fp32 -> Xt [B][T][512] bf16.
// ---------------------------------------------------------------------------
__global__ __launch_bounds__(256) void prep_xt(
    const float* __restrict__ x, bf16* __restrict__ xt)
{
    __shared__ short tile[64 * 72];   // [t][c]
    const int t0 = blockIdx.x * 64;
    const int c0 = blockIdx.y * 64;
    const int b  = blockIdx.z;
    const int tid = threadIdx.x;

    const float* X = x + (size_t)b * DIM_ * T_;

    const int c_l = tid >> 4;          // 0..15
    const int t4  = (tid & 15) * 4;    // 0..60
#pragma unroll
    for (int cp = 0; cp < 4; ++cp) {
        const int c = cp * 16 + c_l;
        f32x4 v = *(const f32x4*)(X + (size_t)(c0 + c) * T_ + t0 + t4);
#pragma unroll
        for (int e = 0; e < 4; ++e) tile[(t4 + e) * 72 + c] = f2bs(v[e]);
    }
    __syncthreads();

    const int t_l = tid >> 2;           // 0..63
    const int c16 = (tid & 3) * 16;     // 0,16,32,48
    short* dst = (short*)xt + ((size_t)b * T_ + t0 + t_l) * DIM_ + c0 + c16;
    *(s16x8*)(dst)     = *(const s16x8*)(&tile[t_l * 72 + c16]);
    *(s16x8*)(dst + 8) = *(const s16x8*)(&tile[t_l * 72 + c16 + 8]);
}

// ---------------------------------------------------------------------------
// QKV projection GEMM: D[t][o] = sum_c Xt[t][c] * W[o][c] + bias[o]
// Tile 128(t) x 64(o), BK=32, 4 waves. Output token-major fp32.
// ---------------------------------------------------------------------------
__global__ __launch_bounds__(256) void gemm_qkv(
    const bf16* __restrict__ xt,
    const float* __restrict__ wq, const float* __restrict__ bq,
    const float* __restrict__ wk, const float* __restrict__ bk,
    const float* __restrict__ wv, const float* __restrict__ bv,
    float* __restrict__ qt, float* __restrict__ kt, float* __restrict__ vt)
{
    const int tt   = blockIdx.x * 128;
    const int ot   = blockIdx.y * 64;
    const int b    = blockIdx.z;
    const int proj = ot >> 9;
    const int orow = ot & 511;
    const int head = orow >> 6;

    const float* W    = (proj == 0) ? wq : (proj == 1) ? wk : wv;
    const float* bsel = (proj == 0) ? bq : (proj == 1) ? bk : bv;
    float*       osel = (proj == 0) ? qt : (proj == 1) ? kt : vt;

    const short* X = (const short*)xt + (size_t)b * T_ * DIM_;

    __shared__ __align__(16) short Xs[128 * LDSTR];
    __shared__ __align__(16) short Ws[64 * LDSTR];

    const int tid  = threadIdx.x;
    const int lane = tid & 63;
    const int wid  = tid >> 6;

    const int row = tid >> 2;
    const int cq  = (tid & 3) * 8;

    f32x4 acc[2][4];
#pragma unroll
    for (int r = 0; r < 2; ++r)
#pragma unroll
        for (int n = 0; n < 4; ++n) acc[r][n] = (f32x4){0.f, 0.f, 0.f, 0.f};

    for (int kk = 0; kk < DIM_; kk += 32) {
#pragma unroll
        for (int rr = 0; rr < 2; ++rr)
            *(s16x8*)(&Xs[(rr * 64 + row) * LDSTR + cq]) =
                *(const s16x8*)(X + (size_t)(tt + rr * 64 + row) * DIM_ + kk + cq);
        *(s16x8*)(&Ws[row * LDSTR + cq]) =
            cvt8(W + (size_t)(orow + row) * DIM_ + kk + cq);
        __syncthreads();

        s16x8 a[2];
#pragma unroll
        for (int r = 0; r < 2; ++r)
            a[r] = *(const s16x8*)(&Xs[(r * 64 + wid * 16 + (lane & 15)) * LDSTR + 8 * (lane >> 4)]);
#pragma unroll
        for (int n = 0; n < 4; ++n) {
            s16x8 bf = *(const s16x8*)(&Ws[(n * 16 + (lane & 15)) * LDSTR + 8 * (lane >> 4)]);
#pragma unroll
            for (int r = 0; r < 2; ++r)
                acc[r][n] = __builtin_amdgcn_mfma_f32_16x16x32_bf16(a[r], bf, acc[r][n], 0, 0, 0);
        }
        __syncthreads();
    }

    float* obase = osel + (size_t)(b * HEADS_ + head) * T_ * HD_;
#pragma unroll
    for (int r = 0; r < 2; ++r)
#pragma unroll
        for (int n = 0; n < 4; ++n) {
            const int d    = n * 16 + (lane & 15);
            const float bi = bsel[orow + d];
#pragma unroll
            for (int e = 0; e < 4; ++e) {
                const int t = tt + r * 64 + wid * 16 + (lane >> 4) * 4 + e;
                obase[(size_t)t * HD_ + d] = acc[r][n][e] + bi;
            }
        }
}

// ---------------------------------------------------------------------------
// Output projection GEMM (unchanged).
// ---------------------------------------------------------------------------
__global__ __launch_bounds__(256) void gemm_out(
    const bf16* __restrict__ ao,
    const float* __restrict__ wo, const float* __restrict__ bo,
    float* __restrict__ out)
{
    const int tt = blockIdx.x * 64;
    const int ot = blockIdx.y * 64;
    const int b  = blockIdx.z;

    const short* X = (const short*)ao + (size_t)b * T_ * DIM_;

    __shared__ __align__(16) short Ws[64 * LDSTR];
    __shared__ __align__(16) short Xs[64 * LDSTR];

    const int tid  = threadIdx.x;
    const int lane = tid & 63;
    const int wid  = tid >> 6;

    const int row = tid >> 2;
    const int cq  = (tid & 3) * 8;

    f32x4 acc[4];
#pragma unroll
    for (int n = 0; n < 4; ++n) acc[n] = (f32x4){0.f, 0.f, 0.f, 0.f};

    for (int kk = 0; kk < DIM_; kk += 32) {
        *(s16x8*)(&Ws[row * LDSTR + cq]) =
            cvt8(wo + (size_t)(ot + row) * DIM_ + kk + cq);
        *(s16x8*)(&Xs[row * LDSTR + cq]) =
            *(const s16x8*)(X + (size_t)(tt + row) * DIM_ + kk + cq);
        __syncthreads();

        s16x8 a = *(const s16x8*)(&Ws[(wid * 16 + (lane & 15)) * LDSTR + 8 * (lane >> 4)]);
#pragma unroll
        for (int n = 0; n < 4; ++n) {
            s16x8 bf = *(const s16x8*)(&Xs[(n * 16 + (lane & 15)) * LDSTR + 8 * (lane >> 4)]);
            acc[n] = __builtin_amdgcn_mfma_f32_16x16x32_bf16(a, bf, acc[n], 0, 0, 0);
        }
        __syncthreads();
    }

    float* obase = out + (size_t)b * DIM_ * T_;
#pragma unroll
    for (int n = 0; n < 4; ++n) {
        const int t = tt + n * 16 + (lane & 15);
#pragma unroll
        for (int e = 0; e < 4; ++e) {
            const int o    = ot + wid * 16 + (lane >> 4) * 4 + e;
            obase[(size_t)o * T_ + t] = acc[n][e] + bo[o];
        }
    }
}

// ---------------------------------------------------------------------------
// MFMA neighborhood attention. Block = (b,h) x 16-token chunk, 4 waves.
// w-space: w = wy*24 + u (u<22 real, wy<7); real w <= 165, S^T over 11
// m-tiles (w<176), PV over K=192 (pads zeroed).
// S^T[w][t] = Kl(A) x Ql(B); softmax wave-local (all waves compute all
// m-tiles); P->LDS bf16 with STATIC acc indexing (wave-uniform owner test,
// rule #20: runtime-indexed ext_vector arrays demote to scratch);
// O[t][d] = Pl(A) x VT(B). fp32 v_s for rejection.
// grid: 2304 blocks of 256, XCD-swizzled.
// ---------------------------------------------------------------------------
__global__ __launch_bounds__(256, 2) void attn_mfma(
    const float* __restrict__ qt, const float* __restrict__ kt,
    const float* __restrict__ vt, bf16* __restrict__ ao)
{
    __shared__ __align__(16) char smem[59648];
    short* Kl = (short*)smem;                            // [176][72]
    short* Ql = (short*)(smem + 25344);                  // [16][72]
    short* VT = (short*)(smem + 25344 + 2304);           // [64][200]
    short* Pl = (short*)(smem + 25344 + 2304 + 25600);   // [16][200]
    float* Ol = (float*)smem;                            // [16][72] alias on Kl

    const int l   = blockIdx.x;
    const int idx = (l & 7) * 288 + (l >> 3);            // XCD-contiguous work
    const int bh  = idx / 144;
    const int rem = idx - bh * 144;
    const int y   = rem / 3;
    const int x0  = (rem % 3) * 16;

    const float* qb = qt + (size_t)bh * T_ * HD_;
    const float* kb = kt + (size_t)bh * T_ * HD_;
    const float* vb = vt + (size_t)bh * T_ * HD_;

    const int tid  = threadIdx.x;
    const int lane = tid & 63;
    const int wv   = tid >> 6;
    const int qq   = lane >> 4;
    const int ln   = lane & 15;

    // ---- stage K rows (bf16), w = wy*24+u ----
    {
        const int c8 = (tid & 7) * 8;
        const int wr = tid >> 3;           // 0..31
#pragma unroll
        for (int p = 0; p < 6; ++p) {
            const int w = p * 32 + wr;
            if (w < 168) {
                const int wy = w / 24, u = w - wy * 24;
                if (u < 22) {
                    const int gy = min(max(y + wy - 3, 0), 47);
                    const int gx = min(max(x0 + u - 3, 0), 47);
                    *(s16x8*)&Kl[w * 72 + c8] =
                        cvt8(kb + (size_t)(gy * 48 + gx) * 64 + c8);
                }
            }
        }
    }
    // ---- stage Q ----
    if (tid < 128) {
        const int t = tid >> 3, c8 = (tid & 7) * 8;
        *(s16x8*)&Ql[t * 72 + c8] = cvt8(qb + (size_t)(y * 48 + x0 + t) * 64 + c8);
    }
    // ---- zero VT pads: w in [168,200) and u-pads {22,23} per wy ----
    {
        const int d = tid >> 2, c = tid & 3;
        *(s16x8*)&VT[d * 200 + 168 + c * 8] = (s16x8){0,0,0,0,0,0,0,0};
    }
#pragma unroll
    for (int pp = 0; pp < 2; ++pp) {
        const int r = pp * 256 + tid;
        if (r < 448) {
            const int wy = r >> 6, d = r & 63;
            *(unsigned*)&VT[d * 200 + wy * 24 + 22] = 0u;
        }
    }
    // ---- zero Pl pads: w in [176,192) ----
    if (tid < 32) {
        const int t = tid >> 1, c = tid & 1;
        *(s16x8*)&Pl[t * 200 + 176 + c * 8] = (s16x8){0,0,0,0,0,0,0,0};
    }
    // ---- stage V transposed: VT[d][w] (e-rotated scatter) ----
    {
        const int rr0 = tid >> 4;          // 0..15
        const int d4  = (tid & 15) * 4;
        const int rot = tid & 3;
#pragma unroll
        for (int p = 0; p < 10; ++p) {
            const int rr = p * 16 + rr0;
            if (rr < 154) {
                const int wy = rr / 22, u = rr - wy * 22;
                const int w  = wy * 24 + u;
                const int gy = min(max(y + wy - 3, 0), 47);
                const int gx = min(max(x0 + u - 3, 0), 47);
                f32x4 v4 = *(const f32x4*)(vb + (size_t)(gy * 48 + gx) * 64 + d4);
#pragma unroll
                for (int e = 0; e < 4; ++e) {
                    const int ee = (e + rot) & 3;
                    VT[(d4 + ee) * 200 + w] = f2bs(v4[ee]);
                }
            }
        }
    }
    __syncthreads();

    // ---- S^T = K x Q^T: 11 m-tiles, 2 k-steps; ALL waves compute all ----
    f32x4 acc[11];
#pragma unroll
    for (int mt = 0; mt < 11; ++mt) acc[mt] = (f32x4){0.f, 0.f, 0.f, 0.f};
#pragma unroll
    for (int ks = 0; ks < 2; ++ks) {
        s16x8 bq_ = *(const s16x8*)&Ql[ln * 72 + ks * 32 + qq * 8];
#pragma unroll
        for (int mt = 0; mt < 11; ++mt) {
            s16x8 ak = *(const s16x8*)&Kl[(mt * 16 + ln) * 72 + ks * 32 + qq * 8];
            acc[mt] = __builtin_amdgcn_mfma_f32_16x16x32_bf16(ak, bq_, acc[mt], 0, 0, 0);
        }
    }

    // ---- mask + wave-local softmax (t = ln; w = mt*16 + qq*4 + e) ----
    const int dx = ln;
    float mxv = -3.0e38f;
#pragma unroll
    for (int mt = 0; mt < 11; ++mt) {
#pragma unroll
        for (int e = 0; e < 4; ++e) {
            const int w  = mt * 16 + qq * 4 + e;
            const int wy = w / 24, u = w - wy * 24;
            const bool valid = (w < 168) &&
                               ((unsigned)(u - dx) <= 6u) &&
                               ((unsigned)(y + wy - 3) < 48u) &&
                               ((unsigned)(x0 + u - 3) < 48u);
            const float s = valid ? acc[mt][e] * 0.125f : -3.0e38f;
            acc[mt][e] = s;
            mxv = fmaxf(mxv, s);
        }
    }
    mxv = fmaxf(mxv, __shfl_xor(mxv, 16));
    mxv = fmaxf(mxv, __shfl_xor(mxv, 32));
    float sum = 0.f;
#pragma unroll
    for (int mt = 0; mt < 11; ++mt)
#pragma unroll
        for (int e = 0; e < 4; ++e) {
            const float p = __expf(acc[mt][e] - mxv);
            acc[mt][e] = p;
            sum += p;
        }
    sum += __shfl_xor(sum, 16);
    sum += __shfl_xor(sum, 32);
    const float inv = 1.0f / sum;

    // ---- write P: compile-time mt, wave-uniform owner test (no scratch) ----
#pragma unroll
    for (int mt = 0; mt < 11; ++mt) {
        const int owner = (mt >= 9) ? 3 : (mt / 3);   // wv0:0-2 wv1:3-5 wv2:6-8 wv3:9-10
        if (wv == owner) {
#pragma unroll
            for (int e = 0; e < 4; ++e) {
                const int w = mt * 16 + qq * 4 + e;
                Pl[ln * 200 + w] = f2bs(acc[mt][e] * inv);
            }
        }
    }
    __syncthreads();

    // ---- O = P x V: one 16-d n-tile per wave, K = 192 ----
    f32x4 oacc = (f32x4){0.f, 0.f, 0.f, 0.f};
#pragma unroll
    for (int ks = 0; ks < 6; ++ks) {
        s16x8 ap  = *(const s16x8*)&Pl[ln * 200 + ks * 32 + qq * 8];
        s16x8 bv_ = *(const s16x8*)&VT[(wv * 16 + ln) * 200 + ks * 32 + qq * 8];
        oacc = __builtin_amdgcn_mfma_f32_16x16x32_bf16(ap, bv_, oacc, 0, 0, 0);
    }
#pragma unroll
    for (int e = 0; e < 4; ++e)
        Ol[(qq * 4 + e) * 72 + wv * 16 + ln] = oacc[e];
    __syncthreads();

    // ---- self-value rejection (fp32 v from global) + store ----
    {
        const int tt = tid >> 4;       // token 0..15
        const int dl = tid & 15;
        const int tg = y * 48 + x0 + tt;
        const float o0 = Ol[tt * 72 + dl],      o1 = Ol[tt * 72 + dl + 16],
                    o2 = Ol[tt * 72 + dl + 32], o3 = Ol[tt * 72 + dl + 48];
        const float* vs = vb + (size_t)tg * 64 + dl;
        const float v0 = vs[0], v1 = vs[16], v2 = vs[32], v3 = vs[48];
        float n2  = v0 * v0 + v1 * v1 + v2 * v2 + v3 * v3;
        float odv = o0 * v0 + o1 * v1 + o2 * v2 + o3 * v3;
#pragma unroll
        for (int off = 1; off < 16; off <<= 1) {
            n2  += __shfl_xor(n2, off);
            odv += __shfl_xor(odv, off);
        }
        const float mxn = fmaxf(sqrtf(n2), 1e-12f);
        const float cf  = odv / (mxn * mxn);
        const int b = bh >> 3, h = bh & 7;
        bf16* dst = ao + ((size_t)b * T_ + tg) * DIM_ + h * 64 + dl;
        dst[0]  = __float2bfloat16(o0 - cf * v0);
        dst[16] = __float2bfloat16(o1 - cf * v1);
        dst[32] = __float2bfloat16(o2 - cf * v2);
        dst[48] = __float2bfloat16(o3 - cf * v3);
    }
}

// ---------------------------------------------------------------------------
extern "C" void kernel_launch(void* const* d_in, const int* in_sizes, int n_in,
                              void* d_out, int out_size, void* d_ws, size_t ws_size,
                              hipStream_t stream)
{
    (void)in_sizes; (void)n_in; (void)out_size; (void)ws_size;

    const float* x  = (const float*)d_in[0];
    const float* wq = (const float*)d_in[1];
    const float* bq = (const float*)d_in[2];
    const float* wk = (const float*)d_in[3];
    const float* bk = (const float*)d_in[4];
    const float* wv = (const float*)d_in[5];
    const float* bv = (const float*)d_in[6];
    const float* wo = (const float*)d_in[7];
    const float* bo = (const float*)d_in[8];
    float* out = (float*)d_out;

    // ws: fp32 q,k,v token-major (28.3 MB) + bf16 Xt/ao buffer (4.7 MB)
    const size_t per = (size_t)B_ * HEADS_ * T_ * HD_;   // 2359296
    float* qt = (float*)d_ws;
    float* kt = qt + per;
    float* vt = kt + per;
    bf16*  xa = (bf16*)(vt + per);    // Xt, later overwritten by ao

    prep_xt<<<dim3(T_ / 64, DIM_ / 64, B_), 256, 0, stream>>>(x, xa);

    dim3 g1(T_ / 128, 1536 / 64, B_);
    gemm_qkv<<<g1, 256, 0, stream>>>(xa, wq, bq, wk, bk, wv, bv, qt, kt, vt);

    attn_mfma<<<dim3(B_ * HEADS_ * (T_ / 16)), 256, 0, stream>>>(qt, kt, vt, xa);

    dim3 g2(T_ / 64, DIM_ / 64, B_);
    gemm_out<<<g2, 256, 0, stream>>>(xa, wo, bo, out);
}

// Round 10
// 73.649 us; speedup vs baseline: 2.9230x; 1.1502x over previous
//
#include <hip/hip_runtime.h>
#include <hip/hip_bf16.h>
#include <math.h>

typedef __hip_bfloat16 bf16;
typedef __attribute__((ext_vector_type(4))) float f32x4;
typedef __attribute__((ext_vector_type(8))) short s16x8;
typedef __attribute__((ext_vector_type(4))) short s16x4;

#define B_     2
#define DIM_   512
#define Hh     48
#define Ww     48
#define T_     2304
#define HEADS_ 8
#define HD_    64
#define NS_    7
#define R_     3
#define KK_    49

#define LDSTR  40   // padded LDS row stride (elems) for GEMM tiles

__device__ __forceinline__ short f2bs(float f) {
    bf16 h = __float2bfloat16(f);
    return *(short*)&h;
}

// load 8 contiguous fp32, convert to 8 bf16 (as shorts)
__device__ __forceinline__ s16x8 cvt8(const float* __restrict__ p) {
    f32x4 a = *(const f32x4*)p;
    f32x4 b = *(const f32x4*)(p + 4);
    s16x8 r;
    r[0] = f2bs(a[0]); r[1] = f2bs(a[1]); r[2] = f2bs(a[2]); r[3] = f2bs(a[3]);
    r[4] = f2bs(b[0]); r[5] = f2bs(b[1]); r[6] = f2bs(b[2]); r[7] = f2bs(b[3]);
    return r;
}

// ---------------------------------------------------------------------------
// prep_xt: transpose-convert X [B][512][T] fp32 -> Xt [B][T][512] bf16.
// ---------------------------------------------------------------------------
__global__ __launch_bounds__(256) void prep_xt(
    const float* __restrict__ x, bf16* __restrict__ xt)
{
    __shared__ short tile[64 * 72];   // [t][c]
    const int t0 = blockIdx.x * 64;
    const int c0 = blockIdx.y * 64;
    const int b  = blockIdx.z;
    const int tid = threadIdx.x;

    const float* X = x + (size_t)b * DIM_ * T_;

    const int c_l = tid >> 4;          // 0..15
    const int t4  = (tid & 15) * 4;    // 0..60
#pragma unroll
    for (int cp = 0; cp < 4; ++cp) {
        const int c = cp * 16 + c_l;
        f32x4 v = *(const f32x4*)(X + (size_t)(c0 + c) * T_ + t0 + t4);
#pragma unroll
        for (int e = 0; e < 4; ++e) tile[(t4 + e) * 72 + c] = f2bs(v[e]);
    }
    __syncthreads();

    const int t_l = tid >> 2;           // 0..63
    const int c16 = (tid & 3) * 16;     // 0,16,32,48
    short* dst = (short*)xt + ((size_t)b * T_ + t0 + t_l) * DIM_ + c0 + c16;
    *(s16x8*)(dst)     = *(const s16x8*)(&tile[t_l * 72 + c16]);
    *(s16x8*)(dst + 8) = *(const s16x8*)(&tile[t_l * 72 + c16 + 8]);
}

// ---------------------------------------------------------------------------
// QKV projection GEMM: D[t][o] = sum_c Xt[t][c] * W[o][c] + bias[o]
// Tile 128(t) x 64(o), BK=32, 4 waves. Outputs: q,k bf16 token-major;
// v fp32 (rejection precision) AND bf16 token-major.
// ---------------------------------------------------------------------------
__global__ __launch_bounds__(256) void gemm_qkv(
    const bf16* __restrict__ xt,
    const float* __restrict__ wq, const float* __restrict__ bq,
    const float* __restrict__ wk, const float* __restrict__ bk,
    const float* __restrict__ wv, const float* __restrict__ bv,
    bf16* __restrict__ qb2, bf16* __restrict__ kb2,
    float* __restrict__ vtf, bf16* __restrict__ vb2)
{
    const int tt   = blockIdx.x * 128;
    const int ot   = blockIdx.y * 64;
    const int b    = blockIdx.z;
    const int proj = ot >> 9;
    const int orow = ot & 511;
    const int head = orow >> 6;

    const float* W    = (proj == 0) ? wq : (proj == 1) ? wk : wv;
    const float* bsel = (proj == 0) ? bq : (proj == 1) ? bk : bv;

    const short* X = (const short*)xt + (size_t)b * T_ * DIM_;

    __shared__ __align__(16) short Xs[128 * LDSTR];
    __shared__ __align__(16) short Ws[64 * LDSTR];

    const int tid  = threadIdx.x;
    const int lane = tid & 63;
    const int wid  = tid >> 6;

    const int row = tid >> 2;
    const int cq  = (tid & 3) * 8;

    f32x4 acc[2][4];
#pragma unroll
    for (int r = 0; r < 2; ++r)
#pragma unroll
        for (int n = 0; n < 4; ++n) acc[r][n] = (f32x4){0.f, 0.f, 0.f, 0.f};

    for (int kk = 0; kk < DIM_; kk += 32) {
#pragma unroll
        for (int rr = 0; rr < 2; ++rr)
            *(s16x8*)(&Xs[(rr * 64 + row) * LDSTR + cq]) =
                *(const s16x8*)(X + (size_t)(tt + rr * 64 + row) * DIM_ + kk + cq);
        *(s16x8*)(&Ws[row * LDSTR + cq]) =
            cvt8(W + (size_t)(orow + row) * DIM_ + kk + cq);
        __syncthreads();

        s16x8 a[2];
#pragma unroll
        for (int r = 0; r < 2; ++r)
            a[r] = *(const s16x8*)(&Xs[(r * 64 + wid * 16 + (lane & 15)) * LDSTR + 8 * (lane >> 4)]);
#pragma unroll
        for (int n = 0; n < 4; ++n) {
            s16x8 bf = *(const s16x8*)(&Ws[(n * 16 + (lane & 15)) * LDSTR + 8 * (lane >> 4)]);
#pragma unroll
            for (int r = 0; r < 2; ++r)
                acc[r][n] = __builtin_amdgcn_mfma_f32_16x16x32_bf16(a[r], bf, acc[r][n], 0, 0, 0);
        }
        __syncthreads();
    }

    const size_t hb = (size_t)(b * HEADS_ + head) * T_ * HD_;
    if (proj < 2) {
        short* ob = (short*)(proj == 0 ? qb2 : kb2) + hb;
#pragma unroll
        for (int r = 0; r < 2; ++r)
#pragma unroll
            for (int n = 0; n < 4; ++n) {
                const int d    = n * 16 + (lane & 15);
                const float bi = bsel[orow + d];
#pragma unroll
                for (int e = 0; e < 4; ++e) {
                    const int t = tt + r * 64 + wid * 16 + (lane >> 4) * 4 + e;
                    ob[(size_t)t * HD_ + d] = f2bs(acc[r][n][e] + bi);
                }
            }
    } else {
        float* of = vtf + hb;
        short* ob = (short*)vb2 + hb;
#pragma unroll
        for (int r = 0; r < 2; ++r)
#pragma unroll
            for (int n = 0; n < 4; ++n) {
                const int d    = n * 16 + (lane & 15);
                const float bi = bsel[orow + d];
#pragma unroll
                for (int e = 0; e < 4; ++e) {
                    const int t = tt + r * 64 + wid * 16 + (lane >> 4) * 4 + e;
                    const float vv = acc[r][n][e] + bi;
                    of[(size_t)t * HD_ + d] = vv;
                    ob[(size_t)t * HD_ + d] = f2bs(vv);
                }
            }
    }
}

// ---------------------------------------------------------------------------
// Output projection GEMM (unchanged).
// ---------------------------------------------------------------------------
__global__ __launch_bounds__(256) void gemm_out(
    const bf16* __restrict__ ao,
    const float* __restrict__ wo, const float* __restrict__ bo,
    float* __restrict__ out)
{
    const int tt = blockIdx.x * 64;
    const int ot = blockIdx.y * 64;
    const int b  = blockIdx.z;

    const short* X = (const short*)ao + (size_t)b * T_ * DIM_;

    __shared__ __align__(16) short Ws[64 * LDSTR];
    __shared__ __align__(16) short Xs[64 * LDSTR];

    const int tid  = threadIdx.x;
    const int lane = tid & 63;
    const int wid  = tid >> 6;

    const int row = tid >> 2;
    const int cq  = (tid & 3) * 8;

    f32x4 acc[4];
#pragma unroll
    for (int n = 0; n < 4; ++n) acc[n] = (f32x4){0.f, 0.f, 0.f, 0.f};

    for (int kk = 0; kk < DIM_; kk += 32) {
        *(s16x8*)(&Ws[row * LDSTR + cq]) =
            cvt8(wo + (size_t)(ot + row) * DIM_ + kk + cq);
        *(s16x8*)(&Xs[row * LDSTR + cq]) =
            *(const s16x8*)(X + (size_t)(tt + row) * DIM_ + kk + cq);
        __syncthreads();

        s16x8 a = *(const s16x8*)(&Ws[(wid * 16 + (lane & 15)) * LDSTR + 8 * (lane >> 4)]);
#pragma unroll
        for (int n = 0; n < 4; ++n) {
            s16x8 bf = *(const s16x8*)(&Xs[(n * 16 + (lane & 15)) * LDSTR + 8 * (lane >> 4)]);
            acc[n] = __builtin_amdgcn_mfma_f32_16x16x32_bf16(a, bf, acc[n], 0, 0, 0);
        }
        __syncthreads();
    }

    float* obase = out + (size_t)b * DIM_ * T_;
#pragma unroll
    for (int n = 0; n < 4; ++n) {
        const int t = tt + n * 16 + (lane & 15);
#pragma unroll
        for (int e = 0; e < 4; ++e) {
            const int o    = ot + wid * 16 + (lane >> 4) * 4 + e;
            obase[(size_t)o * T_ + t] = acc[n][e] + bo[o];
        }
    }
}

// ---------------------------------------------------------------------------
// MFMA neighborhood attention. Block = (b,h) x 16-token chunk, 4 waves.
// bf16 q/k/v sources (pure copy staging, no cvt). LDS 53248B -> 3 blocks/CU:
// Pl aliases dead Kl region (extra barrier before P-write), Ol at Kl+8192.
// S^T = Kl x Ql; wave-local softmax; O = Pl x VT; fp32 v for rejection.
// grid: 2304 blocks of 256, XCD-swizzled.
// ---------------------------------------------------------------------------
__global__ __launch_bounds__(256, 3) void attn_mfma(
    const bf16* __restrict__ qb2, const bf16* __restrict__ kb2,
    const float* __restrict__ vtf, const bf16* __restrict__ vb2,
    bf16* __restrict__ ao)
{
    __shared__ __align__(16) char smem[53248];
    short* Kl = (short*)smem;                            // [176][72] (S phase)
    short* Ql = (short*)(smem + 25344);                  // [16][72]
    short* VT = (short*)(smem + 25344 + 2304);           // [64][200]
    short* Pl = (short*)smem;                            // [16][200] alias Kl (PV phase)
    float* Ol = (float*)(smem + 8192);                   // [16][72] alias Kl tail

    const int l   = blockIdx.x;
    const int idx = (l & 7) * 288 + (l >> 3);            // XCD-contiguous work
    const int bh  = idx / 144;
    const int rem = idx - bh * 144;
    const int y   = rem / 3;
    const int x0  = (rem % 3) * 16;

    const short* qb = (const short*)qb2 + (size_t)bh * T_ * HD_;
    const short* kb = (const short*)kb2 + (size_t)bh * T_ * HD_;
    const short* vbb = (const short*)vb2 + (size_t)bh * T_ * HD_;
    const float* vbf = vtf + (size_t)bh * T_ * HD_;

    const int tid  = threadIdx.x;
    const int lane = tid & 63;
    const int wv   = tid >> 6;
    const int qq   = lane >> 4;
    const int ln   = lane & 15;

    // ---- stage K rows (bf16 copy), w = wy*24+u ----
    {
        const int c8 = (tid & 7) * 8;
        const int wr = tid >> 3;           // 0..31
#pragma unroll
        for (int p = 0; p < 6; ++p) {
            const int w = p * 32 + wr;
            if (w < 168) {
                const int wy = w / 24, u = w - wy * 24;
                if (u < 22) {
                    const int gy = min(max(y + wy - 3, 0), 47);
                    const int gx = min(max(x0 + u - 3, 0), 47);
                    *(s16x8*)&Kl[w * 72 + c8] =
                        *(const s16x8*)(kb + (size_t)(gy * 48 + gx) * 64 + c8);
                }
            }
        }
    }
    // ---- stage Q ----
    if (tid < 128) {
        const int t = tid >> 3, c8 = (tid & 7) * 8;
        *(s16x8*)&Ql[t * 72 + c8] =
            *(const s16x8*)(qb + (size_t)(y * 48 + x0 + t) * 64 + c8);
    }
    // ---- zero VT pads: w in [168,200) and u-pads {22,23} per wy ----
    {
        const int d = tid >> 2, c = tid & 3;
        *(s16x8*)&VT[d * 200 + 168 + c * 8] = (s16x8){0,0,0,0,0,0,0,0};
    }
#pragma unroll
    for (int pp = 0; pp < 2; ++pp) {
        const int r = pp * 256 + tid;
        if (r < 448) {
            const int wy = r >> 6, d = r & 63;
            *(unsigned*)&VT[d * 200 + wy * 24 + 22] = 0u;
        }
    }
    // ---- stage V transposed: VT[d][w] (bf16 source, e-rotated scatter) ----
    {
        const int rr0 = tid >> 4;          // 0..15
        const int d4  = (tid & 15) * 4;
        const int rot = tid & 3;
#pragma unroll
        for (int p = 0; p < 10; ++p) {
            const int rr = p * 16 + rr0;
            if (rr < 154) {
                const int wy = rr / 22, u = rr - wy * 22;
                const int w  = wy * 24 + u;
                const int gy = min(max(y + wy - 3, 0), 47);
                const int gx = min(max(x0 + u - 3, 0), 47);
                s16x4 v4 = *(const s16x4*)(vbb + (size_t)(gy * 48 + gx) * 64 + d4);
#pragma unroll
                for (int e = 0; e < 4; ++e) {
                    const int ee = (e + rot) & 3;
                    VT[(d4 + ee) * 200 + w] = v4[ee];
                }
            }
        }
    }
    __syncthreads();

    // ---- S^T = K x Q^T: 11 m-tiles, 2 k-steps; ALL waves compute all ----
    f32x4 acc[11];
#pragma unroll
    for (int mt = 0; mt < 11; ++mt) acc[mt] = (f32x4){0.f, 0.f, 0.f, 0.f};
#pragma unroll
    for (int ks = 0; ks < 2; ++ks) {
        s16x8 bq_ = *(const s16x8*)&Ql[ln * 72 + ks * 32 + qq * 8];
#pragma unroll
        for (int mt = 0; mt < 11; ++mt) {
            s16x8 ak = *(const s16x8*)&Kl[(mt * 16 + ln) * 72 + ks * 32 + qq * 8];
            acc[mt] = __builtin_amdgcn_mfma_f32_16x16x32_bf16(ak, bq_, acc[mt], 0, 0, 0);
        }
    }

    // ---- mask + wave-local softmax (t = ln; w = mt*16 + qq*4 + e) ----
    const int dx = ln;
    float mxv = -3.0e38f;
#pragma unroll
    for (int mt = 0; mt < 11; ++mt) {
#pragma unroll
        for (int e = 0; e < 4; ++e) {
            const int w  = mt * 16 + qq * 4 + e;
            const int wy = w / 24, u = w - wy * 24;
            const bool valid = (w < 168) &&
                               ((unsigned)(u - dx) <= 6u) &&
                               ((unsigned)(y + wy - 3) < 48u) &&
                               ((unsigned)(x0 + u - 3) < 48u);
            const float s = valid ? acc[mt][e] * 0.125f : -3.0e38f;
            acc[mt][e] = s;
            mxv = fmaxf(mxv, s);
        }
    }
    mxv = fmaxf(mxv, __shfl_xor(mxv, 16));
    mxv = fmaxf(mxv, __shfl_xor(mxv, 32));
    float sum = 0.f;
#pragma unroll
    for (int mt = 0; mt < 11; ++mt)
#pragma unroll
        for (int e = 0; e < 4; ++e) {
            const float p = __expf(acc[mt][e] - mxv);
            acc[mt][e] = p;
            sum += p;
        }
    sum += __shfl_xor(sum, 16);
    sum += __shfl_xor(sum, 32);
    const float inv = 1.0f / sum;

    __syncthreads();   // all waves done reading Kl before Pl (alias) writes

    // ---- zero Pl pads: w in [176,192) ----
    if (tid < 32) {
        const int t = tid >> 1, c = tid & 1;
        *(s16x8*)&Pl[t * 200 + 176 + c * 8] = (s16x8){0,0,0,0,0,0,0,0};
    }
    // ---- write P: compile-time mt, wave-uniform owner test (no scratch) ----
#pragma unroll
    for (int mt = 0; mt < 11; ++mt) {
        const int owner = (mt >= 9) ? 3 : (mt / 3);   // wv0:0-2 wv1:3-5 wv2:6-8 wv3:9-10
        if (wv == owner) {
#pragma unroll
            for (int e = 0; e < 4; ++e) {
                const int w = mt * 16 + qq * 4 + e;
                Pl[ln * 200 + w] = f2bs(acc[mt][e] * inv);
            }
        }
    }
    __syncthreads();

    // ---- O = P x V: one 16-d n-tile per wave, K = 192 ----
    f32x4 oacc = (f32x4){0.f, 0.f, 0.f, 0.f};
#pragma unroll
    for (int ks = 0; ks < 6; ++ks) {
        s16x8 ap  = *(const s16x8*)&Pl[ln * 200 + ks * 32 + qq * 8];
        s16x8 bv_ = *(const s16x8*)&VT[(wv * 16 + ln) * 200 + ks * 32 + qq * 8];
        oacc = __builtin_amdgcn_mfma_f32_16x16x32_bf16(ap, bv_, oacc, 0, 0, 0);
    }
#pragma unroll
    for (int e = 0; e < 4; ++e)
        Ol[(qq * 4 + e) * 72 + wv * 16 + ln] = oacc[e];
    __syncthreads();

    // ---- self-value rejection (fp32 v from global) + store ----
    {
        const int tt = tid >> 4;       // token 0..15
        const int dl = tid & 15;
        const int tg = y * 48 + x0 + tt;
        const float o0 = Ol[tt * 72 + dl],      o1 = Ol[tt * 72 + dl + 16],
                    o2 = Ol[tt * 72 + dl + 32], o3 = Ol[tt * 72 + dl + 48];
        const float* vs = vbf + (size_t)tg * 64 + dl;
        const float v0 = vs[0], v1 = vs[16], v2 = vs[32], v3 = vs[48];
        float n2  = v0 * v0 + v1 * v1 + v2 * v2 + v3 * v3;
        float odv = o0 * v0 + o1 * v1 + o2 * v2 + o3 * v3;
#pragma unroll
        for (int off = 1; off < 16; off <<= 1) {
            n2  += __shfl_xor(n2, off);
            odv += __shfl_xor(odv, off);
        }
        const float mxn = fmaxf(sqrtf(n2), 1e-12f);
        const float cf  = odv / (mxn * mxn);
        const int b = bh >> 3, h = bh & 7;
        bf16* dst = ao + ((size_t)b * T_ + tg) * DIM_ + h * 64 + dl;
        dst[0]  = __float2bfloat16(o0 - cf * v0);
        dst[16] = __float2bfloat16(o1 - cf * v1);
        dst[32] = __float2bfloat16(o2 - cf * v2);
        dst[48] = __float2bfloat16(o3 - cf * v3);
    }
}

// ---------------------------------------------------------------------------
extern "C" void kernel_launch(void* const* d_in, const int* in_sizes, int n_in,
                              void* d_out, int out_size, void* d_ws, size_t ws_size,
                              hipStream_t stream)
{
    (void)in_sizes; (void)n_in; (void)out_size; (void)ws_size;

    const float* x  = (const float*)d_in[0];
    const float* wq = (const float*)d_in[1];
    const float* bq = (const float*)d_in[2];
    const float* wk = (const float*)d_in[3];
    const float* bk = (const float*)d_in[4];
    const float* wv = (const float*)d_in[5];
    const float* bv = (const float*)d_in[6];
    const float* wo = (const float*)d_in[7];
    const float* bo = (const float*)d_in[8];
    float* out = (float*)d_out;

    // ws: v fp32 (9.4MB) + q,k,v bf16 (3x4.7MB) + Xt/ao bf16 (4.7MB) ~28MB
    const size_t per = (size_t)B_ * HEADS_ * T_ * HD_;   // 2359296
    float* vtf = (float*)d_ws;
    bf16*  qb2 = (bf16*)(vtf + per);
    bf16*  kb2 = qb2 + per;
    bf16*  vb2 = kb2 + per;
    bf16*  xa  = vb2 + per;           // Xt, later overwritten by ao

    prep_xt<<<dim3(T_ / 64, DIM_ / 64, B_), 256, 0, stream>>>(x, xa);

    dim3 g1(T_ / 128, 1536 / 64, B_);
    gemm_qkv<<<g1, 256, 0, stream>>>(xa, wq, bq, wk, bk, wv, bv, qb2, kb2, vtf, vb2);

    attn_mfma<<<dim3(B_ * HEADS_ * (T_ / 16)), 256, 0, stream>>>(qb2, kb2, vtf, vb2, xa);

    dim3 g2(T_ / 64, DIM_ / 64, B_);
    gemm_out<<<g2, 256, 0, stream>>>(xa, wo, bo, out);
}

// Round 11
// 70.252 us; speedup vs baseline: 3.0643x; 1.0484x over previous
//
#include <hip/hip_runtime.h>
#include <hip/hip_bf16.h>
#include <math.h>

typedef __hip_bfloat16 bf16;
typedef __attribute__((ext_vector_type(4))) float f32x4;
typedef __attribute__((ext_vector_type(8))) short s16x8;
typedef __attribute__((ext_vector_type(4))) short s16x4;

#define B_     2
#define DIM_   512
#define Hh     48
#define Ww     48
#define T_     2304
#define HEADS_ 8
#define HD_    64
#define NS_    7
#define R_     3
#define KK_    49

#define LDSTR  40   // padded LDS row stride (elems) for GEMM tiles

__device__ __forceinline__ short f2bs(float f) {
    bf16 h = __float2bfloat16(f);
    return *(short*)&h;
}

// load 8 contiguous fp32, convert to 8 bf16 (as shorts)
__device__ __forceinline__ s16x8 cvt8(const float* __restrict__ p) {
    f32x4 a = *(const f32x4*)p;
    f32x4 b = *(const f32x4*)(p + 4);
    s16x8 r;
    r[0] = f2bs(a[0]); r[1] = f2bs(a[1]); r[2] = f2bs(a[2]); r[3] = f2bs(a[3]);
    r[4] = f2bs(b[0]); r[5] = f2bs(b[1]); r[6] = f2bs(b[2]); r[7] = f2bs(b[3]);
    return r;
}

// ---------------------------------------------------------------------------
// wcvt: convert wq|wk|wv|wo (4 x 512x512 fp32) -> bf16 ws buffer.
// grid 512 x 256: one 8-elem chunk per thread.
// ---------------------------------------------------------------------------
__global__ __launch_bounds__(256) void wcvt(
    const float* __restrict__ wq, const float* __restrict__ wk,
    const float* __restrict__ wv, const float* __restrict__ wo,
    bf16* __restrict__ wb)
{
    const int i     = blockIdx.x * 256 + threadIdx.x;   // chunk id
    const int which = i >> 15;                          // 32768 chunks / matrix
    const int off   = (i & 32767) * 8;
    const float* src = (which == 0) ? wq : (which == 1) ? wk : (which == 2) ? wv : wo;
    *(s16x8*)((short*)wb + which * 262144 + off) = cvt8(src + off);
}

// ---------------------------------------------------------------------------
// prep_xt: transpose-convert X [B][512][T] fp32 -> Xt [B][T][512] bf16.
// ---------------------------------------------------------------------------
__global__ __launch_bounds__(256) void prep_xt(
    const float* __restrict__ x, bf16* __restrict__ xt)
{
    __shared__ short tile[64 * 72];   // [t][c]
    const int t0 = blockIdx.x * 64;
    const int c0 = blockIdx.y * 64;
    const int b  = blockIdx.z;
    const int tid = threadIdx.x;

    const float* X = x + (size_t)b * DIM_ * T_;

    const int c_l = tid >> 4;          // 0..15
    const int t4  = (tid & 15) * 4;    // 0..60
#pragma unroll
    for (int cp = 0; cp < 4; ++cp) {
        const int c = cp * 16 + c_l;
        f32x4 v = *(const f32x4*)(X + (size_t)(c0 + c) * T_ + t0 + t4);
#pragma unroll
        for (int e = 0; e < 4; ++e) tile[(t4 + e) * 72 + c] = f2bs(v[e]);
    }
    __syncthreads();

    const int t_l = tid >> 2;           // 0..63
    const int c16 = (tid & 3) * 16;     // 0,16,32,48
    short* dst = (short*)xt + ((size_t)b * T_ + t0 + t_l) * DIM_ + c0 + c16;
    *(s16x8*)(dst)     = *(const s16x8*)(&tile[t_l * 72 + c16]);
    *(s16x8*)(dst + 8) = *(const s16x8*)(&tile[t_l * 72 + c16 + 8]);
}

// ---------------------------------------------------------------------------
// QKV projection GEMM: D[t][o] = sum_c Xt[t][c] * W[o][c] + bias[o]
// Tile 128(t) x 64(o), BK=32, 4 waves. All-bf16 copy staging (wb).
// Outputs: q,k bf16 token-major; v fp32 + bf16.
// ---------------------------------------------------------------------------
__global__ __launch_bounds__(256) void gemm_qkv(
    const bf16* __restrict__ xt, const bf16* __restrict__ wb,
    const float* __restrict__ bq, const float* __restrict__ bk,
    const float* __restrict__ bv,
    bf16* __restrict__ qb2, bf16* __restrict__ kb2,
    float* __restrict__ vtf, bf16* __restrict__ vb2)
{
    const int tt   = blockIdx.x * 128;
    const int ot   = blockIdx.y * 64;
    const int b    = blockIdx.z;
    const int proj = ot >> 9;
    const int orow = ot & 511;
    const int head = orow >> 6;

    const float* bsel = (proj == 0) ? bq : (proj == 1) ? bk : bv;
    const short* Wb   = (const short*)wb + proj * 262144;

    const short* X = (const short*)xt + (size_t)b * T_ * DIM_;

    __shared__ __align__(16) short Xs[128 * LDSTR];
    __shared__ __align__(16) short Ws[64 * LDSTR];

    const int tid  = threadIdx.x;
    const int lane = tid & 63;
    const int wid  = tid >> 6;

    const int row = tid >> 2;
    const int cq  = (tid & 3) * 8;

    f32x4 acc[2][4];
#pragma unroll
    for (int r = 0; r < 2; ++r)
#pragma unroll
        for (int n = 0; n < 4; ++n) acc[r][n] = (f32x4){0.f, 0.f, 0.f, 0.f};

    for (int kk = 0; kk < DIM_; kk += 32) {
#pragma unroll
        for (int rr = 0; rr < 2; ++rr)
            *(s16x8*)(&Xs[(rr * 64 + row) * LDSTR + cq]) =
                *(const s16x8*)(X + (size_t)(tt + rr * 64 + row) * DIM_ + kk + cq);
        *(s16x8*)(&Ws[row * LDSTR + cq]) =
            *(const s16x8*)(Wb + (size_t)(orow + row) * DIM_ + kk + cq);
        __syncthreads();

        s16x8 a[2];
#pragma unroll
        for (int r = 0; r < 2; ++r)
            a[r] = *(const s16x8*)(&Xs[(r * 64 + wid * 16 + (lane & 15)) * LDSTR + 8 * (lane >> 4)]);
#pragma unroll
        for (int n = 0; n < 4; ++n) {
            s16x8 bf = *(const s16x8*)(&Ws[(n * 16 + (lane & 15)) * LDSTR + 8 * (lane >> 4)]);
#pragma unroll
            for (int r = 0; r < 2; ++r)
                acc[r][n] = __builtin_amdgcn_mfma_f32_16x16x32_bf16(a[r], bf, acc[r][n], 0, 0, 0);
        }
        __syncthreads();
    }

    const size_t hb = (size_t)(b * HEADS_ + head) * T_ * HD_;
    if (proj < 2) {
        short* ob = (short*)(proj == 0 ? qb2 : kb2) + hb;
#pragma unroll
        for (int r = 0; r < 2; ++r)
#pragma unroll
            for (int n = 0; n < 4; ++n) {
                const int d    = n * 16 + (lane & 15);
                const float bi = bsel[orow + d];
#pragma unroll
                for (int e = 0; e < 4; ++e) {
                    const int t = tt + r * 64 + wid * 16 + (lane >> 4) * 4 + e;
                    ob[(size_t)t * HD_ + d] = f2bs(acc[r][n][e] + bi);
                }
            }
    } else {
        float* of = vtf + hb;
        short* ob = (short*)vb2 + hb;
#pragma unroll
        for (int r = 0; r < 2; ++r)
#pragma unroll
            for (int n = 0; n < 4; ++n) {
                const int d    = n * 16 + (lane & 15);
                const float bi = bsel[orow + d];
#pragma unroll
                for (int e = 0; e < 4; ++e) {
                    const int t = tt + r * 64 + wid * 16 + (lane >> 4) * 4 + e;
                    const float vv = acc[r][n][e] + bi;
                    of[(size_t)t * HD_ + d] = vv;
                    ob[(size_t)t * HD_ + d] = f2bs(vv);
                }
            }
    }
}

// ---------------------------------------------------------------------------
// Output projection GEMM: W from pre-converted bf16.
// ---------------------------------------------------------------------------
__global__ __launch_bounds__(256) void gemm_out(
    const bf16* __restrict__ ao, const bf16* __restrict__ wb,
    const float* __restrict__ bo, float* __restrict__ out)
{
    const int tt = blockIdx.x * 64;
    const int ot = blockIdx.y * 64;
    const int b  = blockIdx.z;

    const short* X  = (const short*)ao + (size_t)b * T_ * DIM_;
    const short* Wb = (const short*)wb + 3 * 262144;

    __shared__ __align__(16) short Ws[64 * LDSTR];
    __shared__ __align__(16) short Xs[64 * LDSTR];

    const int tid  = threadIdx.x;
    const int lane = tid & 63;
    const int wid  = tid >> 6;

    const int row = tid >> 2;
    const int cq  = (tid & 3) * 8;

    f32x4 acc[4];
#pragma unroll
    for (int n = 0; n < 4; ++n) acc[n] = (f32x4){0.f, 0.f, 0.f, 0.f};

    for (int kk = 0; kk < DIM_; kk += 32) {
        *(s16x8*)(&Ws[row * LDSTR + cq]) =
            *(const s16x8*)(Wb + (size_t)(ot + row) * DIM_ + kk + cq);
        *(s16x8*)(&Xs[row * LDSTR + cq]) =
            *(const s16x8*)(X + (size_t)(tt + row) * DIM_ + kk + cq);
        __syncthreads();

        s16x8 a = *(const s16x8*)(&Ws[(wid * 16 + (lane & 15)) * LDSTR + 8 * (lane >> 4)]);
#pragma unroll
        for (int n = 0; n < 4; ++n) {
            s16x8 bf = *(const s16x8*)(&Xs[(n * 16 + (lane & 15)) * LDSTR + 8 * (lane >> 4)]);
            acc[n] = __builtin_amdgcn_mfma_f32_16x16x32_bf16(a, bf, acc[n], 0, 0, 0);
        }
        __syncthreads();
    }

    float* obase = out + (size_t)b * DIM_ * T_;
#pragma unroll
    for (int n = 0; n < 4; ++n) {
        const int t = tt + n * 16 + (lane & 15);
#pragma unroll
        for (int e = 0; e < 4; ++e) {
            const int o    = ot + wid * 16 + (lane >> 4) * 4 + e;
            obase[(size_t)o * T_ + t] = acc[n][e] + bo[o];
        }
    }
}

// ---------------------------------------------------------------------------
// MFMA neighborhood attention. Block = (b,h) x 16-token chunk, 4 waves.
// LDS 34048B -> 4 blocks/CU: VT aliases (Kl+Ql) after S-phase; Ol aliases Pl
// after PV. V reg-staged (T14): loads issued before bar1, LDS-written after
// bar2 (latency hidden under QK^T + softmax). 5 barriers.
// grid: 2304 blocks of 256, XCD-swizzled.
// ---------------------------------------------------------------------------
__global__ __launch_bounds__(256, 4) void attn_mfma(
    const bf16* __restrict__ qb2, const bf16* __restrict__ kb2,
    const float* __restrict__ vtf, const bf16* __restrict__ vb2,
    bf16* __restrict__ ao)
{
    __shared__ __align__(16) char smem[34048];
    short* Kl = (short*)smem;                 // [176][72]        (S phase)
    short* Ql = (short*)(smem + 25344);       // [16][72]         (S phase)
    short* VT = (short*)smem;                 // [64][200] alias  (PV phase)
    short* Pl = (short*)(smem + 27648);       // [16][200]        (private)
    float* Ol = (float*)(smem + 27648);       // [16][72] alias Pl (epilogue)

    const int l   = blockIdx.x;
    const int idx = (l & 7) * 288 + (l >> 3);            // XCD-contiguous work
    const int bh  = idx / 144;
    const int rem = idx - bh * 144;
    const int y   = rem / 3;
    const int x0  = (rem % 3) * 16;

    const short* qb  = (const short*)qb2 + (size_t)bh * T_ * HD_;
    const short* kb  = (const short*)kb2 + (size_t)bh * T_ * HD_;
    const short* vbb = (const short*)vb2 + (size_t)bh * T_ * HD_;
    const float* vbf = vtf + (size_t)bh * T_ * HD_;

    const int tid  = threadIdx.x;
    const int lane = tid & 63;
    const int wv   = tid >> 6;
    const int qq   = lane >> 4;
    const int ln   = lane & 15;

    // ---- zero Pl pads (private region, safe before bar1) ----
    if (tid < 32) {
        const int t = tid >> 1, c = tid & 1;
        *(s16x8*)&Pl[t * 200 + 176 + c * 8] = (s16x8){0,0,0,0,0,0,0,0};
    }
    // ---- stage K rows (bf16 copy), w = wy*24+u ----
    {
        const int c8 = (tid & 7) * 8;
        const int wr = tid >> 3;           // 0..31
#pragma unroll
        for (int p = 0; p < 6; ++p) {
            const int w = p * 32 + wr;
            if (w < 168) {
                const int wy = w / 24, u = w - wy * 24;
                if (u < 22) {
                    const int gy = min(max(y + wy - 3, 0), 47);
                    const int gx = min(max(x0 + u - 3, 0), 47);
                    *(s16x8*)&Kl[w * 72 + c8] =
                        *(const s16x8*)(kb + (size_t)(gy * 48 + gx) * 64 + c8);
                }
            }
        }
    }
    // ---- stage Q ----
    if (tid < 128) {
        const int t = tid >> 3, c8 = (tid & 7) * 8;
        *(s16x8*)&Ql[t * 72 + c8] =
            *(const s16x8*)(qb + (size_t)(y * 48 + x0 + t) * 64 + c8);
    }
    // ---- issue V loads to regs (T14: write to LDS after bar2) ----
    s16x4 vreg[10];
    {
        const int rr0 = tid >> 4;          // 0..15
        const int d4  = (tid & 15) * 4;
#pragma unroll
        for (int p = 0; p < 10; ++p) {
            const int rr = p * 16 + rr0;
            if (rr < 154) {
                const int wy = rr / 22, u = rr - wy * 22;
                const int gy = min(max(y + wy - 3, 0), 47);
                const int gx = min(max(x0 + u - 3, 0), 47);
                vreg[p] = *(const s16x4*)(vbb + (size_t)(gy * 48 + gx) * 64 + d4);
            }
        }
    }
    __syncthreads();   // bar1: Kl, Ql ready

    // ---- S^T = K x Q^T: 11 m-tiles, 2 k-steps; ALL waves compute all ----
    f32x4 acc[11];
#pragma unroll
    for (int mt = 0; mt < 11; ++mt) acc[mt] = (f32x4){0.f, 0.f, 0.f, 0.f};
#pragma unroll
    for (int ks = 0; ks < 2; ++ks) {
        s16x8 bq_ = *(const s16x8*)&Ql[ln * 72 + ks * 32 + qq * 8];
#pragma unroll
        for (int mt = 0; mt < 11; ++mt) {
            s16x8 ak = *(const s16x8*)&Kl[(mt * 16 + ln) * 72 + ks * 32 + qq * 8];
            acc[mt] = __builtin_amdgcn_mfma_f32_16x16x32_bf16(ak, bq_, acc[mt], 0, 0, 0);
        }
    }

    // ---- mask + wave-local softmax (t = ln; w = mt*16 + qq*4 + e) ----
    const int dx = ln;
    float mxv = -3.0e38f;
#pragma unroll
    for (int mt = 0; mt < 11; ++mt) {
#pragma unroll
        for (int e = 0; e < 4; ++e) {
            const int w  = mt * 16 + qq * 4 + e;
            const int wy = w / 24, u = w - wy * 24;
            const bool valid = (w < 168) &&
                               ((unsigned)(u - dx) <= 6u) &&
                               ((unsigned)(y + wy - 3) < 48u) &&
                               ((unsigned)(x0 + u - 3) < 48u);
            const float s = valid ? acc[mt][e] * 0.125f : -3.0e38f;
            acc[mt][e] = s;
            mxv = fmaxf(mxv, s);
        }
    }
    mxv = fmaxf(mxv, __shfl_xor(mxv, 16));
    mxv = fmaxf(mxv, __shfl_xor(mxv, 32));
    float sum = 0.f;
#pragma unroll
    for (int mt = 0; mt < 11; ++mt)
#pragma unroll
        for (int e = 0; e < 4; ++e) {
            const float p = __expf(acc[mt][e] - mxv);
            acc[mt][e] = p;
            sum += p;
        }
    sum += __shfl_xor(sum, 16);
    sum += __shfl_xor(sum, 32);
    const float inv = 1.0f / sum;

    // ---- write P: compile-time mt, wave-uniform owner (Pl is private) ----
#pragma unroll
    for (int mt = 0; mt < 11; ++mt) {
        const int owner = (mt >= 9) ? 3 : (mt / 3);
        if (wv == owner) {
#pragma unroll
            for (int e = 0; e < 4; ++e) {
                const int w = mt * 16 + qq * 4 + e;
                Pl[ln * 200 + w] = f2bs(acc[mt][e] * inv);
            }
        }
    }
    __syncthreads();   // bar2: all Kl/Ql reads done -> VT may overwrite

    // ---- zero VT pads + write VT from regs ----
    {
        const int d = tid >> 2, c = tid & 3;
        *(s16x8*)&VT[d * 200 + 168 + c * 8] = (s16x8){0,0,0,0,0,0,0,0};
    }
#pragma unroll
    for (int pp = 0; pp < 2; ++pp) {
        const int r2 = pp * 256 + tid;
        if (r2 < 448) {
            const int wy = r2 >> 6, d = r2 & 63;
            *(unsigned*)&VT[d * 200 + wy * 24 + 22] = 0u;
        }
    }
    {
        const int rr0 = tid >> 4;
        const int d4  = (tid & 15) * 4;
        const int rot = tid & 3;
#pragma unroll
        for (int p = 0; p < 10; ++p) {
            const int rr = p * 16 + rr0;
            if (rr < 154) {
                const int wy = rr / 22, u = rr - wy * 22;
                const int w  = wy * 24 + u;
#pragma unroll
                for (int e = 0; e < 4; ++e) {
                    const int ee = (e + rot) & 3;
                    VT[(d4 + ee) * 200 + w] = vreg[p][ee];
                }
            }
        }
    }
    __syncthreads();   // bar3: VT + Pl ready

    // ---- O = P x V: one 16-d n-tile per wave, K = 192 ----
    f32x4 oacc = (f32x4){0.f, 0.f, 0.f, 0.f};
#pragma unroll
    for (int ks = 0; ks < 6; ++ks) {
        s16x8 ap  = *(const s16x8*)&Pl[ln * 200 + ks * 32 + qq * 8];
        s16x8 bv_ = *(const s16x8*)&VT[(wv * 16 + ln) * 200 + ks * 32 + qq * 8];
        oacc = __builtin_amdgcn_mfma_f32_16x16x32_bf16(ap, bv_, oacc, 0, 0, 0);
    }
    __syncthreads();   // bar4: all Pl/VT reads done -> Ol (alias Pl) may write
#pragma unroll
    for (int e = 0; e < 4; ++e)
        Ol[(qq * 4 + e) * 72 + wv * 16 + ln] = oacc[e];
    __syncthreads();   // bar5: Ol ready

    // ---- self-value rejection (fp32 v from global) + store ----
    {
        const int tt = tid >> 4;       // token 0..15
        const int dl = tid & 15;
        const int tg = y * 48 + x0 + tt;
        const float o0 = Ol[tt * 72 + dl],      o1 = Ol[tt * 72 + dl + 16],
                    o2 = Ol[tt * 72 + dl + 32], o3 = Ol[tt * 72 + dl + 48];
        const float* vs = vbf + (size_t)tg * 64 + dl;
        const float v0 = vs[0], v1 = vs[16], v2 = vs[32], v3 = vs[48];
        float n2  = v0 * v0 + v1 * v1 + v2 * v2 + v3 * v3;
        float odv = o0 * v0 + o1 * v1 + o2 * v2 + o3 * v3;
#pragma unroll
        for (int off = 1; off < 16; off <<= 1) {
            n2  += __shfl_xor(n2, off);
            odv += __shfl_xor(odv, off);
        }
        const float mxn = fmaxf(sqrtf(n2), 1e-12f);
        const float cf  = odv / (mxn * mxn);
        const int b = bh >> 3, h = bh & 7;
        bf16* dst = ao + ((size_t)b * T_ + tg) * DIM_ + h * 64 + dl;
        dst[0]  = __float2bfloat16(o0 - cf * v0);
        dst[16] = __float2bfloat16(o1 - cf * v1);
        dst[32] = __float2bfloat16(o2 - cf * v2);
        dst[48] = __float2bfloat16(o3 - cf * v3);
    }
}

// ---------------------------------------------------------------------------
extern "C" void kernel_launch(void* const* d_in, const int* in_sizes, int n_in,
                              void* d_out, int out_size, void* d_ws, size_t ws_size,
                              hipStream_t stream)
{
    (void)in_sizes; (void)n_in; (void)out_size; (void)ws_size;

    const float* x  = (const float*)d_in[0];
    const float* wq = (const float*)d_in[1];
    const float* bq = (const float*)d_in[2];
    const float* wk = (const float*)d_in[3];
    const float* bk = (const float*)d_in[4];
    const float* wv = (const float*)d_in[5];
    const float* bv = (const float*)d_in[6];
    const float* wo = (const float*)d_in[7];
    const float* bo = (const float*)d_in[8];
    float* out = (float*)d_out;

    // ws: v fp32 9.4 + q,k,v bf16 14.2 + Xt/ao 4.7 + Wb bf16 2.0 = ~30.4 MB
    const size_t per = (size_t)B_ * HEADS_ * T_ * HD_;   // 2359296
    float* vtf = (float*)d_ws;
    bf16*  qb2 = (bf16*)(vtf + per);
    bf16*  kb2 = qb2 + per;
    bf16*  vb2 = kb2 + per;
    bf16*  xa  = vb2 + per;           // Xt, later overwritten by ao
    bf16*  wb  = xa + per;            // 4 x 512x512 bf16 weights

    wcvt<<<dim3(512), 256, 0, stream>>>(wq, wk, wv, wo, wb);
    prep_xt<<<dim3(T_ / 64, DIM_ / 64, B_), 256, 0, stream>>>(x, xa);

    dim3 g1(T_ / 128, 1536 / 64, B_);
    gemm_qkv<<<g1, 256, 0, stream>>>(xa, wb, bq, bk, bv, qb2, kb2, vtf, vb2);

    attn_mfma<<<dim3(B_ * HEADS_ * (T_ / 16)), 256, 0, stream>>>(qb2, kb2, vtf, vb2, xa);

    dim3 g2(T_ / 64, DIM_ / 64, B_);
    gemm_out<<<g2, 256, 0, stream>>>(xa, wb, bo, out);
}

// Round 12
// 66.031 us; speedup vs baseline: 3.2602x; 1.0639x over previous
//
#include <hip/hip_runtime.h>
#include <hip/hip_bf16.h>
#include <math.h>

typedef __hip_bfloat16 bf16;
typedef __attribute__((ext_vector_type(4))) float f32x4;
typedef __attribute__((ext_vector_type(8))) short s16x8;
typedef __attribute__((ext_vector_type(4))) short s16x4;

#define B_     2
#define DIM_   512
#define Hh     48
#define Ww     48
#define T_     2304
#define HEADS_ 8
#define HD_    64
#define NS_    7
#define R_     3
#define KK_    49

#define LDSTR  40   // padded LDS row stride (elems) for GEMM tiles

__device__ __forceinline__ short f2bs(float f) {
    bf16 h = __float2bfloat16(f);
    return *(short*)&h;
}

__device__ __forceinline__ float bs2f(short s) {
    bf16 h = *reinterpret_cast<const bf16*>(&s);
    return __bfloat162float(h);
}

// load 8 contiguous fp32, convert to 8 bf16 (as shorts)
__device__ __forceinline__ s16x8 cvt8(const float* __restrict__ p) {
    f32x4 a = *(const f32x4*)p;
    f32x4 b = *(const f32x4*)(p + 4);
    s16x8 r;
    r[0] = f2bs(a[0]); r[1] = f2bs(a[1]); r[2] = f2bs(a[2]); r[3] = f2bs(a[3]);
    r[4] = f2bs(b[0]); r[5] = f2bs(b[1]); r[6] = f2bs(b[2]); r[7] = f2bs(b[3]);
    return r;
}

// ---------------------------------------------------------------------------
// prep: fused weight-convert + X transpose-convert.
// blocks [0,512): wq|wk|wv|wo fp32 -> wb bf16 (one 8-chunk per thread).
// blocks [512,1088): X [B][512][T] fp32 -> Xt [B][T][512] bf16 (64x64 tiles).
// ---------------------------------------------------------------------------
__global__ __launch_bounds__(256) void prep(
    const float* __restrict__ x,
    const float* __restrict__ wq, const float* __restrict__ wk,
    const float* __restrict__ wv, const float* __restrict__ wo,
    bf16* __restrict__ xt, bf16* __restrict__ wb)
{
    __shared__ short tile[64 * 72];   // [t][c]
    const int gid = blockIdx.x;
    const int tid = threadIdx.x;

    if (gid < 512) {
        const int i     = gid * 256 + tid;
        const int which = i >> 15;
        const int off   = (i & 32767) * 8;
        const float* src = (which == 0) ? wq : (which == 1) ? wk
                         : (which == 2) ? wv : wo;
        *(s16x8*)((short*)wb + which * 262144 + off) = cvt8(src + off);
        return;
    }

    const int pid = gid - 512;
    const int b   = pid / 288;
    const int rem = pid - b * 288;
    const int t0  = (rem % 36) * 64;
    const int c0  = (rem / 36) * 64;

    const float* X = x + (size_t)b * DIM_ * T_;

    const int c_l = tid >> 4;          // 0..15
    const int t4  = (tid & 15) * 4;    // 0..60
#pragma unroll
    for (int cp = 0; cp < 4; ++cp) {
        const int c = cp * 16 + c_l;
        f32x4 v = *(const f32x4*)(X + (size_t)(c0 + c) * T_ + t0 + t4);
#pragma unroll
        for (int e = 0; e < 4; ++e) tile[(t4 + e) * 72 + c] = f2bs(v[e]);
    }
    __syncthreads();

    const int t_l = tid >> 2;           // 0..63
    const int c16 = (tid & 3) * 16;     // 0,16,32,48
    short* dst = (short*)xt + ((size_t)b * T_ + t0 + t_l) * DIM_ + c0 + c16;
    *(s16x8*)(dst)     = *(const s16x8*)(&tile[t_l * 72 + c16]);
    *(s16x8*)(dst + 8) = *(const s16x8*)(&tile[t_l * 72 + c16 + 8]);
}

// ---------------------------------------------------------------------------
// QKV projection GEMM: D[t][o] = sum_c Xt[t][c] * W[o][c] + bias[o]
// Tile 128(t) x 128(o), BK=32, 4 waves, 16 MFMA/wave/k-step.
// 128-channel tile spans 2 heads (hn = n>>2). All outputs bf16 token-major.
// grid: (18, 12, 2), block 256.
// ---------------------------------------------------------------------------
__global__ __launch_bounds__(256) void gemm_qkv(
    const bf16* __restrict__ xt, const bf16* __restrict__ wb,
    const float* __restrict__ bq, const float* __restrict__ bk,
    const float* __restrict__ bv,
    bf16* __restrict__ qb2, bf16* __restrict__ kb2, bf16* __restrict__ vb2)
{
    const int tt   = blockIdx.x * 128;
    const int ot   = blockIdx.y * 128;          // [0,1536)
    const int b    = blockIdx.z;
    const int proj = ot >> 9;
    const int orow = ot & 511;                  // {0,128,256,384}
    const int h0   = orow >> 6;                 // head base {0,2,4,6}

    const float* bsel = (proj == 0) ? bq : (proj == 1) ? bk : bv;
    const short* Wb   = (const short*)wb + proj * 262144;
    const short* X    = (const short*)xt + (size_t)b * T_ * DIM_;
    short*       sel  = (short*)((proj == 0) ? qb2 : (proj == 1) ? kb2 : vb2);

    __shared__ __align__(16) short Xs[128 * LDSTR];
    __shared__ __align__(16) short Ws[128 * LDSTR];

    const int tid  = threadIdx.x;
    const int lane = tid & 63;
    const int wid  = tid >> 6;
    const int ln   = lane & 15;

    const int row = tid >> 2;          // 0..63
    const int cq  = (tid & 3) * 8;

    f32x4 acc[2][8];
#pragma unroll
    for (int r = 0; r < 2; ++r)
#pragma unroll
        for (int n = 0; n < 8; ++n) acc[r][n] = (f32x4){0.f, 0.f, 0.f, 0.f};

    for (int kk = 0; kk < DIM_; kk += 32) {
#pragma unroll
        for (int rr = 0; rr < 2; ++rr) {
            *(s16x8*)(&Xs[(rr * 64 + row) * LDSTR + cq]) =
                *(const s16x8*)(X + (size_t)(tt + rr * 64 + row) * DIM_ + kk + cq);
            *(s16x8*)(&Ws[(rr * 64 + row) * LDSTR + cq]) =
                *(const s16x8*)(Wb + (size_t)(orow + rr * 64 + row) * DIM_ + kk + cq);
        }
        __syncthreads();

        s16x8 a[2];
#pragma unroll
        for (int r = 0; r < 2; ++r)
            a[r] = *(const s16x8*)(&Xs[(r * 64 + wid * 16 + ln) * LDSTR + 8 * (lane >> 4)]);
#pragma unroll
        for (int n = 0; n < 8; ++n) {
            s16x8 bf = *(const s16x8*)(&Ws[(n * 16 + ln) * LDSTR + 8 * (lane >> 4)]);
#pragma unroll
            for (int r = 0; r < 2; ++r)
                acc[r][n] = __builtin_amdgcn_mfma_f32_16x16x32_bf16(a[r], bf, acc[r][n], 0, 0, 0);
        }
        __syncthreads();
    }

    // epilogue: col = n*16+ln spans 2 heads; hn = n>>2, d = (n&3)*16+ln
    const size_t tb = (size_t)(b * HEADS_ + h0);
#pragma unroll
    for (int r = 0; r < 2; ++r)
#pragma unroll
        for (int n = 0; n < 8; ++n) {
            const int hn   = n >> 2;
            const int d    = (n & 3) * 16 + ln;
            const float bi = bsel[orow + n * 16 + ln];
#pragma unroll
            for (int e = 0; e < 4; ++e) {
                const int t = tt + r * 64 + wid * 16 + (lane >> 4) * 4 + e;
                sel[((tb + hn) * T_ + t) * HD_ + d] = f2bs(acc[r][n][e] + bi);
            }
        }
}

// ---------------------------------------------------------------------------
// Output projection GEMM (unchanged core).
// ---------------------------------------------------------------------------
__global__ __launch_bounds__(256) void gemm_out(
    const bf16* __restrict__ ao, const bf16* __restrict__ wb,
    const float* __restrict__ bo, float* __restrict__ out)
{
    const int tt = blockIdx.x * 64;
    const int ot = blockIdx.y * 64;
    const int b  = blockIdx.z;

    const short* X  = (const short*)ao + (size_t)b * T_ * DIM_;
    const short* Wb = (const short*)wb + 3 * 262144;

    __shared__ __align__(16) short Ws[64 * LDSTR];
    __shared__ __align__(16) short Xs[64 * LDSTR];

    const int tid  = threadIdx.x;
    const int lane = tid & 63;
    const int wid  = tid >> 6;

    const int row = tid >> 2;
    const int cq  = (tid & 3) * 8;

    f32x4 acc[4];
#pragma unroll
    for (int n = 0; n < 4; ++n) acc[n] = (f32x4){0.f, 0.f, 0.f, 0.f};

    for (int kk = 0; kk < DIM_; kk += 32) {
        *(s16x8*)(&Ws[row * LDSTR + cq]) =
            *(const s16x8*)(Wb + (size_t)(ot + row) * DIM_ + kk + cq);
        *(s16x8*)(&Xs[row * LDSTR + cq]) =
            *(const s16x8*)(X + (size_t)(tt + row) * DIM_ + kk + cq);
        __syncthreads();

        s16x8 a = *(const s16x8*)(&Ws[(wid * 16 + (lane & 15)) * LDSTR + 8 * (lane >> 4)]);
#pragma unroll
        for (int n = 0; n < 4; ++n) {
            s16x8 bf = *(const s16x8*)(&Xs[(n * 16 + (lane & 15)) * LDSTR + 8 * (lane >> 4)]);
            acc[n] = __builtin_amdgcn_mfma_f32_16x16x32_bf16(a, bf, acc[n], 0, 0, 0);
        }
        __syncthreads();
    }

    float* obase = out + (size_t)b * DIM_ * T_;
#pragma unroll
    for (int n = 0; n < 4; ++n) {
        const int t = tt + n * 16 + (lane & 15);
#pragma unroll
        for (int e = 0; e < 4; ++e) {
            const int o    = ot + wid * 16 + (lane >> 4) * 4 + e;
            obase[(size_t)o * T_ + t] = acc[n][e] + bo[o];
        }
    }
}

// ---------------------------------------------------------------------------
// MFMA neighborhood attention. Block = (b,h) x 16-token chunk, 4 waves.
// LDS 34048B -> 4 blocks/CU; VT aliases (Kl+Ql); Ol aliases Pl. V reg-staged.
// Rejection v from bf16 vb2. grid: 2304 blocks of 256, XCD-swizzled.
// ---------------------------------------------------------------------------
__global__ __launch_bounds__(256, 4) void attn_mfma(
    const bf16* __restrict__ qb2, const bf16* __restrict__ kb2,
    const bf16* __restrict__ vb2, bf16* __restrict__ ao)
{
    __shared__ __align__(16) char smem[34048];
    short* Kl = (short*)smem;                 // [176][72]        (S phase)
    short* Ql = (short*)(smem + 25344);       // [16][72]         (S phase)
    short* VT = (short*)smem;                 // [64][200] alias  (PV phase)
    short* Pl = (short*)(smem + 27648);       // [16][200]        (private)
    float* Ol = (float*)(smem + 27648);       // [16][72] alias Pl (epilogue)

    const int l   = blockIdx.x;
    const int idx = (l & 7) * 288 + (l >> 3);            // XCD-contiguous work
    const int bh  = idx / 144;
    const int rem = idx - bh * 144;
    const int y   = rem / 3;
    const int x0  = (rem % 3) * 16;

    const short* qb  = (const short*)qb2 + (size_t)bh * T_ * HD_;
    const short* kb  = (const short*)kb2 + (size_t)bh * T_ * HD_;
    const short* vbb = (const short*)vb2 + (size_t)bh * T_ * HD_;

    const int tid  = threadIdx.x;
    const int lane = tid & 63;
    const int wv   = tid >> 6;
    const int qq   = lane >> 4;
    const int ln   = lane & 15;

    // ---- zero Pl pads (private region, safe before bar1) ----
    if (tid < 32) {
        const int t = tid >> 1, c = tid & 1;
        *(s16x8*)&Pl[t * 200 + 176 + c * 8] = (s16x8){0,0,0,0,0,0,0,0};
    }
    // ---- stage K rows (bf16 copy), w = wy*24+u ----
    {
        const int c8 = (tid & 7) * 8;
        const int wr = tid >> 3;           // 0..31
#pragma unroll
        for (int p = 0; p < 6; ++p) {
            const int w = p * 32 + wr;
            if (w < 168) {
                const int wy = w / 24, u = w - wy * 24;
                if (u < 22) {
                    const int gy = min(max(y + wy - 3, 0), 47);
                    const int gx = min(max(x0 + u - 3, 0), 47);
                    *(s16x8*)&Kl[w * 72 + c8] =
                        *(const s16x8*)(kb + (size_t)(gy * 48 + gx) * 64 + c8);
                }
            }
        }
    }
    // ---- stage Q ----
    if (tid < 128) {
        const int t = tid >> 3, c8 = (tid & 7) * 8;
        *(s16x8*)&Ql[t * 72 + c8] =
            *(const s16x8*)(qb + (size_t)(y * 48 + x0 + t) * 64 + c8);
    }
    // ---- issue V loads to regs (T14: write to LDS after bar2) ----
    s16x4 vreg[10];
    {
        const int rr0 = tid >> 4;          // 0..15
        const int d4  = (tid & 15) * 4;
#pragma unroll
        for (int p = 0; p < 10; ++p) {
            const int rr = p * 16 + rr0;
            if (rr < 154) {
                const int wy = rr / 22, u = rr - wy * 22;
                const int gy = min(max(y + wy - 3, 0), 47);
                const int gx = min(max(x0 + u - 3, 0), 47);
                vreg[p] = *(const s16x4*)(vbb + (size_t)(gy * 48 + gx) * 64 + d4);
            }
        }
    }
    __syncthreads();   // bar1: Kl, Ql ready

    // ---- S^T = K x Q^T: 11 m-tiles, 2 k-steps; ALL waves compute all ----
    f32x4 acc[11];
#pragma unroll
    for (int mt = 0; mt < 11; ++mt) acc[mt] = (f32x4){0.f, 0.f, 0.f, 0.f};
#pragma unroll
    for (int ks = 0; ks < 2; ++ks) {
        s16x8 bq_ = *(const s16x8*)&Ql[ln * 72 + ks * 32 + qq * 8];
#pragma unroll
        for (int mt = 0; mt < 11; ++mt) {
            s16x8 ak = *(const s16x8*)&Kl[(mt * 16 + ln) * 72 + ks * 32 + qq * 8];
            acc[mt] = __builtin_amdgcn_mfma_f32_16x16x32_bf16(ak, bq_, acc[mt], 0, 0, 0);
        }
    }

    // ---- mask + wave-local softmax (t = ln; w = mt*16 + qq*4 + e) ----
    const int dx = ln;
    float mxv = -3.0e38f;
#pragma unroll
    for (int mt = 0; mt < 11; ++mt) {
#pragma unroll
        for (int e = 0; e < 4; ++e) {
            const int w  = mt * 16 + qq * 4 + e;
            const int wy = w / 24, u = w - wy * 24;
            const bool valid = (w < 168) &&
                               ((unsigned)(u - dx) <= 6u) &&
                               ((unsigned)(y + wy - 3) < 48u) &&
                               ((unsigned)(x0 + u - 3) < 48u);
            const float s = valid ? acc[mt][e] * 0.125f : -3.0e38f;
            acc[mt][e] = s;
            mxv = fmaxf(mxv, s);
        }
    }
    mxv = fmaxf(mxv, __shfl_xor(mxv, 16));
    mxv = fmaxf(mxv, __shfl_xor(mxv, 32));
    float sum = 0.f;
#pragma unroll
    for (int mt = 0; mt < 11; ++mt)
#pragma unroll
        for (int e = 0; e < 4; ++e) {
            const float p = __expf(acc[mt][e] - mxv);
            acc[mt][e] = p;
            sum += p;
        }
    sum += __shfl_xor(sum, 16);
    sum += __shfl_xor(sum, 32);
    const float inv = 1.0f / sum;

    // ---- write P: compile-time mt, wave-uniform owner (Pl is private) ----
#pragma unroll
    for (int mt = 0; mt < 11; ++mt) {
        const int owner = (mt >= 9) ? 3 : (mt / 3);
        if (wv == owner) {
#pragma unroll
            for (int e = 0; e < 4; ++e) {
                const int w = mt * 16 + qq * 4 + e;
                Pl[ln * 200 + w] = f2bs(acc[mt][e] * inv);
            }
        }
    }
    __syncthreads();   // bar2: all Kl/Ql reads done -> VT may overwrite

    // ---- zero VT pads + write VT from regs ----
    {
        const int d = tid >> 2, c = tid & 3;
        *(s16x8*)&VT[d * 200 + 168 + c * 8] = (s16x8){0,0,0,0,0,0,0,0};
    }
#pragma unroll
    for (int pp = 0; pp < 2; ++pp) {
        const int r2 = pp * 256 + tid;
        if (r2 < 448) {
            const int wy = r2 >> 6, d = r2 & 63;
            *(unsigned*)&VT[d * 200 + wy * 24 + 22] = 0u;
        }
    }
    {
        const int rr0 = tid >> 4;
        const int d4  = (tid & 15) * 4;
        const int rot = tid & 3;
#pragma unroll
        for (int p = 0; p < 10; ++p) {
            const int rr = p * 16 + rr0;
            if (rr < 154) {
                const int wy = rr / 22, u = rr - wy * 22;
                const int w  = wy * 24 + u;
#pragma unroll
                for (int e = 0; e < 4; ++e) {
                    const int ee = (e + rot) & 3;
                    VT[(d4 + ee) * 200 + w] = vreg[p][ee];
                }
            }
        }
    }
    __syncthreads();   // bar3: VT + Pl ready

    // ---- O = P x V: one 16-d n-tile per wave, K = 192 ----
    f32x4 oacc = (f32x4){0.f, 0.f, 0.f, 0.f};
#pragma unroll
    for (int ks = 0; ks < 6; ++ks) {
        s16x8 ap  = *(const s16x8*)&Pl[ln * 200 + ks * 32 + qq * 8];
        s16x8 bv_ = *(const s16x8*)&VT[(wv * 16 + ln) * 200 + ks * 32 + qq * 8];
        oacc = __builtin_amdgcn_mfma_f32_16x16x32_bf16(ap, bv_, oacc, 0, 0, 0);
    }
    __syncthreads();   // bar4: all Pl/VT reads done -> Ol (alias Pl) may write
#pragma unroll
    for (int e = 0; e < 4; ++e)
        Ol[(qq * 4 + e) * 72 + wv * 16 + ln] = oacc[e];
    __syncthreads();   // bar5: Ol ready

    // ---- self-value rejection (bf16 v) + store ----
    {
        const int tt = tid >> 4;       // token 0..15
        const int dl = tid & 15;
        const int tg = y * 48 + x0 + tt;
        const float o0 = Ol[tt * 72 + dl],      o1 = Ol[tt * 72 + dl + 16],
                    o2 = Ol[tt * 72 + dl + 32], o3 = Ol[tt * 72 + dl + 48];
        const short* vs = vbb + (size_t)tg * 64 + dl;
        const float v0 = bs2f(vs[0]),  v1 = bs2f(vs[16]),
                    v2 = bs2f(vs[32]), v3 = bs2f(vs[48]);
        float n2  = v0 * v0 + v1 * v1 + v2 * v2 + v3 * v3;
        float odv = o0 * v0 + o1 * v1 + o2 * v2 + o3 * v3;
#pragma unroll
        for (int off = 1; off < 16; off <<= 1) {
            n2  += __shfl_xor(n2, off);
            odv += __shfl_xor(odv, off);
        }
        const float mxn = fmaxf(sqrtf(n2), 1e-12f);
        const float cf  = odv / (mxn * mxn);
        const int b = bh >> 3, h = bh & 7;
        bf16* dst = ao + ((size_t)b * T_ + tg) * DIM_ + h * 64 + dl;
        dst[0]  = __float2bfloat16(o0 - cf * v0);
        dst[16] = __float2bfloat16(o1 - cf * v1);
        dst[32] = __float2bfloat16(o2 - cf * v2);
        dst[48] = __float2bfloat16(o3 - cf * v3);
    }
}

// ---------------------------------------------------------------------------
extern "C" void kernel_launch(void* const* d_in, const int* in_sizes, int n_in,
                              void* d_out, int out_size, void* d_ws, size_t ws_size,
                              hipStream_t stream)
{
    (void)in_sizes; (void)n_in; (void)out_size; (void)ws_size;

    const float* x  = (const float*)d_in[0];
    const float* wq = (const float*)d_in[1];
    const float* bq = (const float*)d_in[2];
    const float* wk = (const float*)d_in[3];
    const float* bk = (const float*)d_in[4];
    const float* wv = (const float*)d_in[5];
    const float* bv = (const float*)d_in[6];
    const float* wo = (const float*)d_in[7];
    const float* bo = (const float*)d_in[8];
    float* out = (float*)d_out;

    // ws: q,k,v bf16 (3x4.7) + Xt/ao (4.7) + Wb (2.0) = ~21 MB
    const size_t per = (size_t)B_ * HEADS_ * T_ * HD_;   // 2359296
    bf16* qb2 = (bf16*)d_ws;
    bf16* kb2 = qb2 + per;
    bf16* vb2 = kb2 + per;
    bf16* xa  = vb2 + per;            // Xt, later overwritten by ao
    bf16* wb  = xa + per;             // 4 x 512x512 bf16 weights

    prep<<<dim3(512 + 576), 256, 0, stream>>>(x, wq, wk, wv, wo, xa, wb);

    dim3 g1(T_ / 128, 1536 / 128, B_);
    gemm_qkv<<<g1, 256, 0, stream>>>(xa, wb, bq, bk, bv, qb2, kb2, vb2);

    attn_mfma<<<dim3(B_ * HEADS_ * (T_ / 16)), 256, 0, stream>>>(qb2, kb2, vb2, xa);

    dim3 g2(T_ / 64, DIM_ / 64, B_);
    gemm_out<<<g2, 256, 0, stream>>>(xa, wb, bo, out);
}